// Round 1
// baseline (430.203 us; speedup 1.0000x reference)
//
#include <hip/hip_runtime.h>
#include <hip/hip_bf16.h>

// Problem constants (from reference)
#define MA 60000
#define PA 20
#define CA 5
#define MR 80000
#define PR 32
#define CR 3
#define NXg 256
#define NYg 256
#define NB 8
#define NCELL (NB * NYg * NXg)   // 524288

typedef __bf16 bf16x8 __attribute__((ext_vector_type(8)));
typedef float  f32x4  __attribute__((ext_vector_type(4)));

__device__ __forceinline__ unsigned short f2bf(float f) {
    unsigned int u = __float_as_uint(f);
    u += 0x7fffu + ((u >> 16) & 1u);   // round-to-nearest-even
    return (unsigned short)(u >> 16);
}

// ---------------------------------------------------------------------------
// Winner-map init (-1 everywhere). win_a and win_r are contiguous: one pass.
__global__ void __launch_bounds__(256) init_win(int* __restrict__ w, int n) {
    int i = blockIdx.x * 256 + threadIdx.x;
    if (i < n) w[i] = -1;
}

// ---------------------------------------------------------------------------
// Pre-pack conv weights (3,3,128,32) fp32 -> bf16 in MFMA B-fragment order:
// element i = (((tap*4 + kk)*2 + nt)*64 + lane)*8 + j
//   n = nt*16 + (lane&15),  k = kk*32 + (lane>>4)*8 + j
__global__ void __launch_bounds__(256) pack_w(const float* __restrict__ conv_w,
                                              unsigned short* __restrict__ bp) {
    int i = blockIdx.x * 256 + threadIdx.x;
    if (i >= 9 * 4 * 2 * 64 * 8) return;
    int j    = i & 7;
    int lane = (i >> 3) & 63;
    int nt   = (i >> 9) & 1;
    int kk   = (i >> 10) & 3;
    int tap  = i >> 12;
    int n = nt * 16 + (lane & 15);
    int k = kk * 32 + (lane >> 4) * 8 + j;
    bp[i] = f2bf(conv_w[(tap * 128 + k) * 32 + n]);
}

// ---------------------------------------------------------------------------
// Pillar VFE: one wave per pillar, lane = output channel d (0..63).
// out[d] = max(0, max_{p<np} (feats_p . Wcol_d + b_d)); also atomicMax winner.
template <int CIN, int CF, int PMAX>
__global__ void __launch_bounds__(256) vfe_kernel(
    const float* __restrict__ vox, const int* __restrict__ coors,
    const int* __restrict__ npts, const float* __restrict__ W,
    const float* __restrict__ bias, unsigned short* __restrict__ feat,
    int* __restrict__ win, int M)
{
    int wv   = threadIdx.x >> 6;
    int lane = threadIdx.x & 63;
    int m    = blockIdx.x * 4 + wv;
    if (m >= M) return;

    int np = npts[m];
    if (np < 1) np = 1;
    if (np > PMAX) np = PMAX;

    const float* v = vox + (long)m * PMAX * CIN;

    // mean of xyz over valid points (wave-uniform scalar-ish loads)
    float sx = 0.f, sy = 0.f, sz = 0.f;
    for (int p = 0; p < np; ++p) {
        sx += v[p * CIN + 0];
        sy += v[p * CIN + 1];
        sz += v[p * CIN + 2];
    }
    float inv = 1.0f / (float)np;
    float mx = sx * inv, my = sy * inv, mz = sz * inv;

    int cy = coors[m * 3 + 1];
    int cx = coors[m * 3 + 2];
    // VX = VY = 0.3125 exactly; X_OFF = -39.84375, Y_OFF = -19.84375 exactly
    float xo = (float)cx * 0.3125f + (-39.84375f);
    float yo = (float)cy * 0.3125f + (-19.84375f);

    float wc[CF];
#pragma unroll
    for (int c = 0; c < CF; ++c) wc[c] = W[c * 64 + lane];
    float bd = bias[lane];

    float best = 0.0f;  // relu floor (masked rows contribute 0, relu >= 0)
    for (int p = 0; p < np; ++p) {
        float f[CF];
#pragma unroll
        for (int c = 0; c < CIN; ++c) f[c] = v[p * CIN + c];
        f[CIN + 0] = f[0] - mx;
        f[CIN + 1] = f[1] - my;
        f[CIN + 2] = f[2] - mz;
        f[CIN + 3] = f[0] - xo;
        f[CIN + 4] = f[1] - yo;
        float d = bd;
#pragma unroll
        for (int c = 0; c < CF; ++c) d = fmaf(f[c], wc[c], d);
        best = fmaxf(best, d);
    }

    feat[(long)m * 64 + lane] = f2bf(best);

    if (lane == 0) {
        int cb = coors[m * 3 + 0];
        // numpy last-write-wins == max pillar index wins
        atomicMax(&win[(cb * NYg + cy) * NXg + cx], m);
    }
}

// ---------------------------------------------------------------------------
// Implicit-GEMM 3x3 conv via MFMA bf16. One wave per tile of 16 x-cells
// (same b,y) x 32 output channels. A gathered through winner maps (sparse
// canvas never materialized). K = 9 taps * 128 ch; 72 MFMAs per wave.
__global__ void __launch_bounds__(256) conv_kernel(
    const unsigned short* __restrict__ feat_a,
    const unsigned short* __restrict__ feat_r,
    const int* __restrict__ win_a, const int* __restrict__ win_r,
    const unsigned short* __restrict__ bpack,
    const float* __restrict__ conv_b,
    float* __restrict__ out)
{
    int lane = threadIdx.x & 63;
    int wv   = threadIdx.x >> 6;
    int tile = blockIdx.x * 4 + wv;   // 0..32767
    int tx = tile & 15;               // x-tile (16 cells)
    int ry = tile >> 4;
    int y  = ry & 255;
    int b  = ry >> 8;

    int mrow = lane & 15;             // A-operand row (cell within tile)
    int quad = lane >> 4;             // k-chunk of 8
    int x = tx * 16 + mrow;

    bf16x8 z;
#pragma unroll
    for (int i = 0; i < 8; ++i) z[i] = (__bf16)0.0f;

    f32x4 acc0 = {0.f, 0.f, 0.f, 0.f};
    f32x4 acc1 = {0.f, 0.f, 0.f, 0.f};

#pragma unroll
    for (int tap = 0; tap < 9; ++tap) {
        const int dy = tap / 3 - 1;
        const int dx = tap % 3 - 1;
        int yy = y + dy;
        if ((unsigned)yy >= (unsigned)NYg) continue;   // wave-uniform skip
        int xx = x + dx;
        bool vx = (unsigned)xx < (unsigned)NXg;        // per-lane edge mask

        int nb = ((b << 8) + yy) * NXg + xx;
        int wa = vx ? win_a[nb] : -1;
        int wr = vx ? win_r[nb] : -1;

        bf16x8 a0 = z, a1 = z, r0 = z, r1 = z;
        if (wa >= 0) {
            const unsigned short* pa = feat_a + ((long)wa << 6) + quad * 8;
            a0 = *(const bf16x8*)(pa);        // agent ch quad*8..+7   (k 0..31)
            a1 = *(const bf16x8*)(pa + 32);   // agent ch 32+quad*8    (k 32..63)
        }
        if (wr >= 0) {
            const unsigned short* pr = feat_r + ((long)wr << 6) + quad * 8;
            r0 = *(const bf16x8*)(pr);        // rg ch quad*8          (k 64..95)
            r1 = *(const bf16x8*)(pr + 32);   // rg ch 32+quad*8       (k 96..127)
        }

        const unsigned short* bp = bpack + tap * 4096 + lane * 8;
        bf16x8 b00 = *(const bf16x8*)(bp);
        bf16x8 b01 = *(const bf16x8*)(bp + 512);
        bf16x8 b10 = *(const bf16x8*)(bp + 1024);
        bf16x8 b11 = *(const bf16x8*)(bp + 1536);
        bf16x8 b20 = *(const bf16x8*)(bp + 2048);
        bf16x8 b21 = *(const bf16x8*)(bp + 2560);
        bf16x8 b30 = *(const bf16x8*)(bp + 3072);
        bf16x8 b31 = *(const bf16x8*)(bp + 3584);

        acc0 = __builtin_amdgcn_mfma_f32_16x16x32_bf16(a0, b00, acc0, 0, 0, 0);
        acc1 = __builtin_amdgcn_mfma_f32_16x16x32_bf16(a0, b01, acc1, 0, 0, 0);
        acc0 = __builtin_amdgcn_mfma_f32_16x16x32_bf16(a1, b10, acc0, 0, 0, 0);
        acc1 = __builtin_amdgcn_mfma_f32_16x16x32_bf16(a1, b11, acc1, 0, 0, 0);
        acc0 = __builtin_amdgcn_mfma_f32_16x16x32_bf16(r0, b20, acc0, 0, 0, 0);
        acc1 = __builtin_amdgcn_mfma_f32_16x16x32_bf16(r0, b21, acc1, 0, 0, 0);
        acc0 = __builtin_amdgcn_mfma_f32_16x16x32_bf16(r1, b30, acc0, 0, 0, 0);
        acc1 = __builtin_amdgcn_mfma_f32_16x16x32_bf16(r1, b31, acc1, 0, 0, 0);
    }

    // D layout: col = lane&15, row = quad*4 + reg (m89/m91-verified)
    int col = lane & 15;
    float bias0 = conv_b[col];
    float bias1 = conv_b[col + 16];
    int rowbase = (((b << 8) + y) << 8) + tx * 16;
#pragma unroll
    for (int r = 0; r < 4; ++r) {
        int row = quad * 4 + r;
        float* o = out + (long)(rowbase + row) * 32;
        o[col]      = acc0[r] + bias0;
        o[col + 16] = acc1[r] + bias1;
    }
}

// ---------------------------------------------------------------------------
extern "C" void kernel_launch(void* const* d_in, const int* in_sizes, int n_in,
                              void* d_out, int out_size, void* d_ws, size_t ws_size,
                              hipStream_t stream)
{
    const float* vox_a  = (const float*)d_in[0];
    const int*   coor_a = (const int*)d_in[1];
    const int*   np_a   = (const int*)d_in[2];
    const float* vox_r  = (const float*)d_in[3];
    const int*   coor_r = (const int*)d_in[4];
    const int*   np_r   = (const int*)d_in[5];
    const float* w_a    = (const float*)d_in[6];
    const float* b_a    = (const float*)d_in[7];
    const float* w_r    = (const float*)d_in[8];
    const float* b_r    = (const float*)d_in[9];
    const float* conv_w = (const float*)d_in[10];
    const float* conv_b = (const float*)d_in[11];
    float* out = (float*)d_out;

    // Workspace layout (all 256B-aligned offsets), total ~21.2 MB
    char* ws = (char*)d_ws;
    unsigned short* feat_a = (unsigned short*)(ws);                        // 7,680,000 B
    unsigned short* feat_r = (unsigned short*)(ws + 7680000);              // 10,240,000 B
    int* win_a             = (int*)(ws + 17920000);                        // 2,097,152 B
    int* win_r             = (int*)(ws + 17920000 + 2097152);              // 2,097,152 B
    unsigned short* bpack  = (unsigned short*)(ws + 17920000 + 2 * 2097152); // 73,728 B

    // 1) winner maps = -1 (both maps contiguous)
    hipLaunchKernelGGL(init_win, dim3((2 * NCELL + 255) / 256), dim3(256), 0, stream,
                       win_a, 2 * NCELL);
    // 2) pack conv weights into B-fragment order (bf16)
    hipLaunchKernelGGL(pack_w, dim3(144), dim3(256), 0, stream, conv_w, bpack);
    // 3) VFE agent: 60000 pillars, 4 waves/block
    hipLaunchKernelGGL((vfe_kernel<CA, CA + 5, PA>), dim3(MA / 4), dim3(256), 0, stream,
                       vox_a, coor_a, np_a, w_a, b_a, feat_a, win_a, MA);
    // 4) VFE rg: 80000 pillars
    hipLaunchKernelGGL((vfe_kernel<CR, CR + 5, PR>), dim3(MR / 4), dim3(256), 0, stream,
                       vox_r, coor_r, np_r, w_r, b_r, feat_r, win_r, MR);
    // 5) implicit-GEMM conv: 32768 tiles, 4 waves/block
    hipLaunchKernelGGL(conv_kernel, dim3(32768 / 4), dim3(256), 0, stream,
                       feat_a, feat_r, win_a, win_r, bpack, conv_b, out);
}

// Round 2
// 352.522 us; speedup vs baseline: 1.2204x; 1.2204x over previous
//
#include <hip/hip_runtime.h>
#include <hip/hip_bf16.h>

// Problem constants (from reference)
#define MA 60000
#define PA 20
#define CA 5
#define MR 80000
#define PR 32
#define CR 3
#define NXg 256
#define NYg 256
#define NB 8
#define NCELL (NB * NYg * NXg)   // 524288

typedef __bf16 bf16x8 __attribute__((ext_vector_type(8)));
typedef float  f32x4  __attribute__((ext_vector_type(4)));
typedef float  f4     __attribute__((ext_vector_type(4)));

__device__ __forceinline__ unsigned short f2bf(float f) {
    unsigned int u = __float_as_uint(f);
    u += 0x7fffu + ((u >> 16) & 1u);   // round-to-nearest-even
    return (unsigned short)(u >> 16);
}

// ---------------------------------------------------------------------------
// Winner-map init (-1 everywhere). Interleaved int2 {agent, rg} per cell.
__global__ void __launch_bounds__(256) init_win(int* __restrict__ w, int n) {
    int i = blockIdx.x * 256 + threadIdx.x;
    if (i < n) w[i] = -1;
}

// ---------------------------------------------------------------------------
// Pre-pack conv weights (3,3,128,32) fp32 -> bf16 in MFMA B-fragment order:
// element i = (((tap*4 + kk)*2 + nt)*64 + lane)*8 + j
//   n = nt*16 + (lane&15),  k = kk*32 + (lane>>4)*8 + j
__global__ void __launch_bounds__(256) pack_w(const float* __restrict__ conv_w,
                                              unsigned short* __restrict__ bp) {
    int i = blockIdx.x * 256 + threadIdx.x;
    if (i >= 9 * 4 * 2 * 64 * 8) return;
    int j    = i & 7;
    int lane = (i >> 3) & 63;
    int nt   = (i >> 9) & 1;
    int kk   = (i >> 10) & 3;
    int tap  = i >> 12;
    int n = nt * 16 + (lane & 15);
    int k = kk * 32 + (lane >> 4) * 8 + j;
    bp[i] = f2bf(conv_w[(tap * 128 + k) * 32 + n]);
}

// ---------------------------------------------------------------------------
// Pillar VFE v2: one wave per pillar, lane = output channel d (0..63).
// Algebra: d_p = sum_c v_pc * we_c + off,  off = b_d - mean.w_cl - xo*w_cx - yo*w_cy
//          out_d = max(0, max_valid_p(s_p) + off)
// Single fully-unrolled pass; float4-vectorized wave-uniform loads; per-lane
// predication for p >= np. No serial load-dependence chain.
template <int CIN, int CF, int PMAX>
__global__ void __launch_bounds__(256) vfe_kernel(
    const float* __restrict__ vox, const int* __restrict__ coors,
    const int* __restrict__ npts, const float* __restrict__ W,
    const float* __restrict__ bias, unsigned short* __restrict__ feat,
    int* __restrict__ win, int M, int which)
{
    int wv   = threadIdx.x >> 6;
    int lane = threadIdx.x & 63;
    int m    = blockIdx.x * 4 + wv;
    if (m >= M) return;

    int np = npts[m];
    np = np < 1 ? 1 : (np > PMAX ? PMAX : np);

    // per-lane weight column + effective (folded) weights
    float wc[CF];
#pragma unroll
    for (int c = 0; c < CF; ++c) wc[c] = W[c * 64 + lane];
    float bd = bias[lane];
    float we[CIN];
    we[0] = wc[0] + wc[CIN + 0] + wc[CIN + 3];
    we[1] = wc[1] + wc[CIN + 1] + wc[CIN + 4];
    we[2] = wc[2] + wc[CIN + 2];
#pragma unroll
    for (int c = 3; c < CIN; ++c) we[c] = wc[c];

    const f4* v4 = (const f4*)(vox + (size_t)m * (PMAX * CIN));

    float sx = 0.f, sy = 0.f, sz = 0.f;
    float sbest = -1e30f;

#pragma unroll
    for (int g = 0; g < PMAX / 4; ++g) {        // groups of 4 points
        f4 q[CIN];                               // 4*CIN floats = CIN float4s
#pragma unroll
        for (int i = 0; i < CIN; ++i) q[i] = v4[g * CIN + i];
#pragma unroll
        for (int j = 0; j < 4; ++j) {
            const int f0 = j * CIN;
            float x = q[(f0 + 0) >> 2][(f0 + 0) & 3];
            float y = q[(f0 + 1) >> 2][(f0 + 1) & 3];
            float z = q[(f0 + 2) >> 2][(f0 + 2) & 3];
            int p = g * 4 + j;
            bool val = p < np;
            sx += val ? x : 0.0f;
            sy += val ? y : 0.0f;
            sz += val ? z : 0.0f;
            float d = fmaf(x, we[0], fmaf(y, we[1], z * we[2]));
#pragma unroll
            for (int c = 3; c < CIN; ++c)
                d = fmaf(q[(f0 + c) >> 2][(f0 + c) & 3], we[c], d);
            sbest = val ? fmaxf(sbest, d) : sbest;
        }
    }

    float inv = 1.0f / (float)np;
    float mx = sx * inv, my = sy * inv, mz = sz * inv;

    int cy = coors[m * 3 + 1];
    int cx = coors[m * 3 + 2];
    float xo = (float)cx * 0.3125f + (-39.84375f);   // VX=0.3125, X_OFF exact
    float yo = (float)cy * 0.3125f + (-19.84375f);

    float off = bd - (mx * wc[CIN + 0] + my * wc[CIN + 1] + mz * wc[CIN + 2])
                   - xo * wc[CIN + 3] - yo * wc[CIN + 4];
    float best = fmaxf(0.0f, sbest + off);

    feat[(size_t)m * 64 + lane] = f2bf(best);

    if (lane == 0) {
        int cb = coors[m * 3 + 0];
        // numpy last-write-wins == max pillar index wins; interleaved int2 map
        atomicMax(&win[((cb * NYg + cy) * NXg + cx) * 2 + which], m);
    }
}

// ---------------------------------------------------------------------------
// Implicit-GEMM 3x3 conv via MFMA bf16. One wave per tile of 16 x-cells
// (same b,y) x 32 output channels. A gathered through winner maps (sparse
// canvas never materialized). K = 9 taps * 128 ch; 72 MFMAs per wave.
__global__ void __launch_bounds__(256) conv_kernel(
    const unsigned short* __restrict__ feat_a,
    const unsigned short* __restrict__ feat_r,
    const int* __restrict__ win,              // int2-interleaved {agent, rg}
    const unsigned short* __restrict__ bpack,
    const float* __restrict__ conv_b,
    float* __restrict__ out)
{
    int lane = threadIdx.x & 63;
    int wv   = threadIdx.x >> 6;
    int tile = blockIdx.x * 4 + wv;   // 0..32767
    int tx = tile & 15;               // x-tile (16 cells)
    int ry = tile >> 4;
    int y  = ry & 255;
    int b  = ry >> 8;

    int mrow = lane & 15;             // A-operand row (cell within tile)
    int quad = lane >> 4;             // k-chunk of 8
    int x = tx * 16 + mrow;

    bf16x8 z;
#pragma unroll
    for (int i = 0; i < 8; ++i) z[i] = (__bf16)0.0f;

    f32x4 acc0 = {0.f, 0.f, 0.f, 0.f};
    f32x4 acc1 = {0.f, 0.f, 0.f, 0.f};

#pragma unroll
    for (int tap = 0; tap < 9; ++tap) {
        const int dy = tap / 3 - 1;
        const int dx = tap % 3 - 1;
        int yy = y + dy;
        if ((unsigned)yy >= (unsigned)NYg) continue;   // wave-uniform skip
        int xx = x + dx;
        bool vx = (unsigned)xx < (unsigned)NXg;        // per-lane edge mask

        int nb = ((b << 8) + yy) * NXg + xx;
        int wa = -1, wr = -1;
        if (vx) {
            int2 w2 = ((const int2*)win)[nb];          // one dwordx2
            wa = w2.x; wr = w2.y;
        }

        bf16x8 a0 = z, a1 = z, r0 = z, r1 = z;
        if (wa >= 0) {
            const unsigned short* pa = feat_a + ((long)wa << 6) + quad * 8;
            a0 = *(const bf16x8*)(pa);        // agent ch quad*8..+7   (k 0..31)
            a1 = *(const bf16x8*)(pa + 32);   // agent ch 32+quad*8    (k 32..63)
        }
        if (wr >= 0) {
            const unsigned short* pr = feat_r + ((long)wr << 6) + quad * 8;
            r0 = *(const bf16x8*)(pr);        // rg ch quad*8          (k 64..95)
            r1 = *(const bf16x8*)(pr + 32);   // rg ch 32+quad*8       (k 96..127)
        }

        const unsigned short* bp = bpack + tap * 4096 + lane * 8;
        bf16x8 b00 = *(const bf16x8*)(bp);
        bf16x8 b01 = *(const bf16x8*)(bp + 512);
        bf16x8 b10 = *(const bf16x8*)(bp + 1024);
        bf16x8 b11 = *(const bf16x8*)(bp + 1536);
        bf16x8 b20 = *(const bf16x8*)(bp + 2048);
        bf16x8 b21 = *(const bf16x8*)(bp + 2560);
        bf16x8 b30 = *(const bf16x8*)(bp + 3072);
        bf16x8 b31 = *(const bf16x8*)(bp + 3584);

        acc0 = __builtin_amdgcn_mfma_f32_16x16x32_bf16(a0, b00, acc0, 0, 0, 0);
        acc1 = __builtin_amdgcn_mfma_f32_16x16x32_bf16(a0, b01, acc1, 0, 0, 0);
        acc0 = __builtin_amdgcn_mfma_f32_16x16x32_bf16(a1, b10, acc0, 0, 0, 0);
        acc1 = __builtin_amdgcn_mfma_f32_16x16x32_bf16(a1, b11, acc1, 0, 0, 0);
        acc0 = __builtin_amdgcn_mfma_f32_16x16x32_bf16(r0, b20, acc0, 0, 0, 0);
        acc1 = __builtin_amdgcn_mfma_f32_16x16x32_bf16(r0, b21, acc1, 0, 0, 0);
        acc0 = __builtin_amdgcn_mfma_f32_16x16x32_bf16(r1, b30, acc0, 0, 0, 0);
        acc1 = __builtin_amdgcn_mfma_f32_16x16x32_bf16(r1, b31, acc1, 0, 0, 0);
    }

    // D layout: col = lane&15, row = quad*4 + reg (m89/m91-verified)
    int col = lane & 15;
    float bias0 = conv_b[col];
    float bias1 = conv_b[col + 16];
    int rowbase = (((b << 8) + y) << 8) + tx * 16;
#pragma unroll
    for (int r = 0; r < 4; ++r) {
        int row = quad * 4 + r;
        float* o = out + (long)(rowbase + row) * 32;
        o[col]      = acc0[r] + bias0;
        o[col + 16] = acc1[r] + bias1;
    }
}

// ---------------------------------------------------------------------------
extern "C" void kernel_launch(void* const* d_in, const int* in_sizes, int n_in,
                              void* d_out, int out_size, void* d_ws, size_t ws_size,
                              hipStream_t stream)
{
    const float* vox_a  = (const float*)d_in[0];
    const int*   coor_a = (const int*)d_in[1];
    const int*   np_a   = (const int*)d_in[2];
    const float* vox_r  = (const float*)d_in[3];
    const int*   coor_r = (const int*)d_in[4];
    const int*   np_r   = (const int*)d_in[5];
    const float* w_a    = (const float*)d_in[6];
    const float* b_a    = (const float*)d_in[7];
    const float* w_r    = (const float*)d_in[8];
    const float* b_r    = (const float*)d_in[9];
    const float* conv_w = (const float*)d_in[10];
    const float* conv_b = (const float*)d_in[11];
    float* out = (float*)d_out;

    // Workspace layout (256B-aligned offsets), total ~22.2 MB
    char* ws = (char*)d_ws;
    unsigned short* feat_a = (unsigned short*)(ws);                          // 7,680,000 B
    unsigned short* feat_r = (unsigned short*)(ws + 7680000);                // 10,240,000 B
    int* win               = (int*)(ws + 17920000);                          // 4,194,304 B (int2/cell)
    unsigned short* bpack  = (unsigned short*)(ws + 17920000 + 4194304);     // 73,728 B

    // 1) winner map = -1
    hipLaunchKernelGGL(init_win, dim3((2 * NCELL + 255) / 256), dim3(256), 0, stream,
                       win, 2 * NCELL);
    // 2) pack conv weights into B-fragment order (bf16)
    hipLaunchKernelGGL(pack_w, dim3(144), dim3(256), 0, stream, conv_w, bpack);
    // 3) VFE agent: 60000 pillars, 4 waves/block
    hipLaunchKernelGGL((vfe_kernel<CA, CA + 5, PA>), dim3(MA / 4), dim3(256), 0, stream,
                       vox_a, coor_a, np_a, w_a, b_a, feat_a, win, MA, 0);
    // 4) VFE rg: 80000 pillars
    hipLaunchKernelGGL((vfe_kernel<CR, CR + 5, PR>), dim3(MR / 4), dim3(256), 0, stream,
                       vox_r, coor_r, np_r, w_r, b_r, feat_r, win, MR, 1);
    // 5) implicit-GEMM conv: 32768 tiles, 4 waves/block
    hipLaunchKernelGGL(conv_kernel, dim3(32768 / 4), dim3(256), 0, stream,
                       feat_a, feat_r, win, bpack, conv_b, out);
}

// Round 3
// 308.838 us; speedup vs baseline: 1.3930x; 1.1414x over previous
//
#include <hip/hip_runtime.h>
#include <hip/hip_bf16.h>

// Problem constants (from reference)
#define MA 60000
#define PA 20
#define CA 5
#define MR 80000
#define PR 32
#define CR 3
#define NXg 256
#define NYg 256
#define NB 8
#define NCELL (NB * NYg * NXg)   // 524288

typedef __bf16 bf16x8 __attribute__((ext_vector_type(8)));
typedef float  f32x4  __attribute__((ext_vector_type(4)));
typedef float  f4     __attribute__((ext_vector_type(4)));

__device__ __forceinline__ unsigned short f2bf(float f) {
    unsigned int u = __float_as_uint(f);
    u += 0x7fffu + ((u >> 16) & 1u);   // round-to-nearest-even
    return (unsigned short)(u >> 16);
}

// ---------------------------------------------------------------------------
// Winner-map init (-1 everywhere). Interleaved int2 {agent, rg} per cell.
__global__ void __launch_bounds__(256) init_win(int* __restrict__ w, int n) {
    int i = blockIdx.x * 256 + threadIdx.x;
    if (i < n) w[i] = -1;
}

// ---------------------------------------------------------------------------
// Pre-pack conv weights (3,3,128,32) fp32 -> bf16 in MFMA B-fragment order:
// element i = (((tap*4 + kk)*2 + nt)*64 + lane)*8 + j
//   n = nt*16 + (lane&15),  k = kk*32 + (lane>>4)*8 + j
__global__ void __launch_bounds__(256) pack_w(const float* __restrict__ conv_w,
                                              unsigned short* __restrict__ bp) {
    int i = blockIdx.x * 256 + threadIdx.x;
    if (i >= 9 * 4 * 2 * 64 * 8) return;
    int j    = i & 7;
    int lane = (i >> 3) & 63;
    int nt   = (i >> 9) & 1;
    int kk   = (i >> 10) & 3;
    int tap  = i >> 12;
    int n = nt * 16 + (lane & 15);
    int k = kk * 32 + (lane >> 4) * 8 + j;
    bp[i] = f2bf(conv_w[(tap * 128 + k) * 32 + n]);
}

// ---------------------------------------------------------------------------
// Pillar VFE v3: one wave per pillar, lane = output channel d (0..63).
// Phase 1: ALL point data loaded into registers (independent float4 loads),
// pinned by sched_barrier so the compiler cannot sink/serialize them.
// Phase 2: fully-unrolled compute with WAVE-UNIFORM group-skip branches
// (np is uniform per pillar -> no divergence; avg np = P/2 halves the VALU).
template <int CIN, int CF, int PMAX>
__global__ void __launch_bounds__(256) vfe_kernel(
    const float* __restrict__ vox, const int* __restrict__ coors,
    const int* __restrict__ npts, const float* __restrict__ W,
    const float* __restrict__ bias, unsigned short* __restrict__ feat,
    int* __restrict__ win, int M, int which)
{
    constexpr int NF4 = (PMAX * CIN) / 4;   // 25 (agent) / 24 (rg)
    constexpr int NG  = PMAX / 4;           // point groups of 4

    int wv   = threadIdx.x >> 6;
    int lane = threadIdx.x & 63;
    int m    = blockIdx.x * 4 + wv;
    if (m >= M) return;

    int np = npts[m];
    np = np < 1 ? 1 : (np > PMAX ? PMAX : np);

    // per-lane weight column + effective (folded) weights
    float wc[CF];
#pragma unroll
    for (int c = 0; c < CF; ++c) wc[c] = W[c * 64 + lane];
    float bd = bias[lane];
    float we[CIN];
    we[0] = wc[0] + wc[CIN + 0] + wc[CIN + 3];
    we[1] = wc[1] + wc[CIN + 1] + wc[CIN + 4];
    we[2] = wc[2] + wc[CIN + 2];
#pragma unroll
    for (int c = 3; c < CIN; ++c) we[c] = wc[c];

    // ---- Phase 1: batch-load the whole pillar (wave-uniform addresses) ----
    const f4* v4 = (const f4*)(vox + (size_t)m * (PMAX * CIN));
    f4 q[NF4];
#pragma unroll
    for (int i = 0; i < NF4; ++i) q[i] = v4[i];
    __builtin_amdgcn_sched_barrier(0);   // keep loads batched ahead of compute

    // ---- Phase 2: compute (uniform early-skip per group of 4 points) ----
    float sx = 0.f, sy = 0.f, sz = 0.f;
    float sbest = -1e30f;
#pragma unroll
    for (int g = 0; g < NG; ++g) {
        if (np > g * 4) {                 // wave-uniform branch
#pragma unroll
            for (int j = 0; j < 4; ++j) {
                const int t0 = (g * 4 + j) * CIN;
                float x = q[(t0 + 0) >> 2][(t0 + 0) & 3];
                float y = q[(t0 + 1) >> 2][(t0 + 1) & 3];
                float z = q[(t0 + 2) >> 2][(t0 + 2) & 3];
                bool val = (g * 4 + j) < np;
                sx += val ? x : 0.0f;
                sy += val ? y : 0.0f;
                sz += val ? z : 0.0f;
                float d = fmaf(x, we[0], fmaf(y, we[1], z * we[2]));
#pragma unroll
                for (int c = 3; c < CIN; ++c)
                    d = fmaf(q[(t0 + c) >> 2][(t0 + c) & 3], we[c], d);
                sbest = val ? fmaxf(sbest, d) : sbest;
            }
        }
    }

    float inv = 1.0f / (float)np;
    float mx = sx * inv, my = sy * inv, mz = sz * inv;

    int cy = coors[m * 3 + 1];
    int cx = coors[m * 3 + 2];
    float xo = (float)cx * 0.3125f + (-39.84375f);   // VX=0.3125, X_OFF exact
    float yo = (float)cy * 0.3125f + (-19.84375f);

    float off = bd - (mx * wc[CIN + 0] + my * wc[CIN + 1] + mz * wc[CIN + 2])
                   - xo * wc[CIN + 3] - yo * wc[CIN + 4];
    float best = fmaxf(0.0f, sbest + off);

    feat[(size_t)m * 64 + lane] = f2bf(best);

    if (lane == 0) {
        int cb = coors[m * 3 + 0];
        // numpy last-write-wins == max pillar index wins; interleaved int2 map
        atomicMax(&win[((cb * NYg + cy) * NXg + cx) * 2 + which], m);
    }
}

// ---------------------------------------------------------------------------
// Implicit-GEMM 3x3 conv via MFMA bf16, v2: one wave = 64 cells (4 Mtiles of
// 16) x 32 output channels. Block = one full canvas row (4 waves x 64 cells),
// so win row + bpack tap-slice are L1-shared. B fragments loaded once per
// tap, reused by 4 Mtiles -> 288 MFMAs : 72 B-loads : 144 gathers per wave.
__global__ void __launch_bounds__(256) conv_kernel(
    const unsigned short* __restrict__ feat_a,
    const unsigned short* __restrict__ feat_r,
    const int2* __restrict__ win2,            // {agent, rg} per cell
    const unsigned short* __restrict__ bpack,
    const float* __restrict__ conv_b,
    float* __restrict__ out)
{
    int lane = threadIdx.x & 63;
    int wv   = threadIdx.x >> 6;
    int row  = blockIdx.x;            // 0..2047  (b*256 + y)
    int y    = row & 255;
    int b    = row >> 8;

    int mrow = lane & 15;             // A-operand row (cell within Mtile)
    int quad = lane >> 4;             // k-chunk of 8
    int xbase = wv * 64;

    bf16x8 z;
#pragma unroll
    for (int i = 0; i < 8; ++i) z[i] = (__bf16)0.0f;

    f32x4 acc0[4], acc1[4];
#pragma unroll
    for (int mt = 0; mt < 4; ++mt) {
        acc0[mt] = (f32x4){0.f, 0.f, 0.f, 0.f};
        acc1[mt] = (f32x4){0.f, 0.f, 0.f, 0.f};
    }

#pragma unroll
    for (int tap = 0; tap < 9; ++tap) {
        const int dy = tap / 3 - 1;
        const int dx = tap % 3 - 1;
        int yy = y + dy;
        if ((unsigned)yy >= (unsigned)NYg) continue;   // wave-uniform skip

        // B fragments for this tap (reused by all 4 Mtiles)
        const unsigned short* bp = bpack + tap * 4096 + lane * 8;
        bf16x8 b00 = *(const bf16x8*)(bp);
        bf16x8 b01 = *(const bf16x8*)(bp + 512);
        bf16x8 b10 = *(const bf16x8*)(bp + 1024);
        bf16x8 b11 = *(const bf16x8*)(bp + 1536);
        bf16x8 b20 = *(const bf16x8*)(bp + 2048);
        bf16x8 b21 = *(const bf16x8*)(bp + 2560);
        bf16x8 b30 = *(const bf16x8*)(bp + 3072);
        bf16x8 b31 = *(const bf16x8*)(bp + 3584);

        int rowoff = ((b << 8) + yy) << 8;             // cell row base

#pragma unroll
        for (int mt = 0; mt < 4; ++mt) {
            int x  = xbase + mt * 16 + mrow;
            int xx = x + dx;
            bool vx = (unsigned)xx < (unsigned)NXg;    // per-lane edge mask

            int wa = -1, wr = -1;
            if (vx) {
                int2 w2 = win2[rowoff + xx];           // one dwordx2, L1-hot
                wa = w2.x; wr = w2.y;
            }

            bf16x8 a0 = z, a1 = z, r0 = z, r1 = z;
            if (wa >= 0) {
                const unsigned short* pa = feat_a + ((long)wa << 6) + (quad << 3);
                a0 = *(const bf16x8*)(pa);        // agent k 0..31
                a1 = *(const bf16x8*)(pa + 32);   // agent k 32..63
            }
            if (wr >= 0) {
                const unsigned short* pr = feat_r + ((long)wr << 6) + (quad << 3);
                r0 = *(const bf16x8*)(pr);        // rg k 64..95
                r1 = *(const bf16x8*)(pr + 32);   // rg k 96..127
            }

            acc0[mt] = __builtin_amdgcn_mfma_f32_16x16x32_bf16(a0, b00, acc0[mt], 0, 0, 0);
            acc1[mt] = __builtin_amdgcn_mfma_f32_16x16x32_bf16(a0, b01, acc1[mt], 0, 0, 0);
            acc0[mt] = __builtin_amdgcn_mfma_f32_16x16x32_bf16(a1, b10, acc0[mt], 0, 0, 0);
            acc1[mt] = __builtin_amdgcn_mfma_f32_16x16x32_bf16(a1, b11, acc1[mt], 0, 0, 0);
            acc0[mt] = __builtin_amdgcn_mfma_f32_16x16x32_bf16(r0, b20, acc0[mt], 0, 0, 0);
            acc1[mt] = __builtin_amdgcn_mfma_f32_16x16x32_bf16(r0, b21, acc1[mt], 0, 0, 0);
            acc0[mt] = __builtin_amdgcn_mfma_f32_16x16x32_bf16(r1, b30, acc0[mt], 0, 0, 0);
            acc1[mt] = __builtin_amdgcn_mfma_f32_16x16x32_bf16(r1, b31, acc1[mt], 0, 0, 0);
        }
    }

    // D layout: col = lane&15, row = quad*4 + reg (m89/m91-verified)
    int col = lane & 15;
    float bias0 = conv_b[col];
    float bias1 = conv_b[col + 16];
    int cellbase = (((b << 8) + y) << 8) + xbase;
#pragma unroll
    for (int mt = 0; mt < 4; ++mt) {
#pragma unroll
        for (int r = 0; r < 4; ++r) {
            int cell = cellbase + mt * 16 + quad * 4 + r;
            float* o = out + (long)cell * 32;
            o[col]      = acc0[mt][r] + bias0;
            o[col + 16] = acc1[mt][r] + bias1;
        }
    }
}

// ---------------------------------------------------------------------------
extern "C" void kernel_launch(void* const* d_in, const int* in_sizes, int n_in,
                              void* d_out, int out_size, void* d_ws, size_t ws_size,
                              hipStream_t stream)
{
    const float* vox_a  = (const float*)d_in[0];
    const int*   coor_a = (const int*)d_in[1];
    const int*   np_a   = (const int*)d_in[2];
    const float* vox_r  = (const float*)d_in[3];
    const int*   coor_r = (const int*)d_in[4];
    const int*   np_r   = (const int*)d_in[5];
    const float* w_a    = (const float*)d_in[6];
    const float* b_a    = (const float*)d_in[7];
    const float* w_r    = (const float*)d_in[8];
    const float* b_r    = (const float*)d_in[9];
    const float* conv_w = (const float*)d_in[10];
    const float* conv_b = (const float*)d_in[11];
    float* out = (float*)d_out;

    // Workspace layout (16B-aligned offsets), total ~22.2 MB
    char* ws = (char*)d_ws;
    unsigned short* feat_a = (unsigned short*)(ws);                          // 7,680,000 B
    unsigned short* feat_r = (unsigned short*)(ws + 7680000);                // 10,240,000 B
    int* win               = (int*)(ws + 17920000);                          // 4,194,304 B (int2/cell)
    unsigned short* bpack  = (unsigned short*)(ws + 17920000 + 4194304);     // 73,728 B

    // 1) winner map = -1
    hipLaunchKernelGGL(init_win, dim3((2 * NCELL + 255) / 256), dim3(256), 0, stream,
                       win, 2 * NCELL);
    // 2) pack conv weights into B-fragment order (bf16)
    hipLaunchKernelGGL(pack_w, dim3(144), dim3(256), 0, stream, conv_w, bpack);
    // 3) VFE agent: 60000 pillars, 4 waves/block
    hipLaunchKernelGGL((vfe_kernel<CA, CA + 5, PA>), dim3(MA / 4), dim3(256), 0, stream,
                       vox_a, coor_a, np_a, w_a, b_a, feat_a, win, MA, 0);
    // 4) VFE rg: 80000 pillars
    hipLaunchKernelGGL((vfe_kernel<CR, CR + 5, PR>), dim3(MR / 4), dim3(256), 0, stream,
                       vox_r, coor_r, np_r, w_r, b_r, feat_r, win, MR, 1);
    // 5) implicit-GEMM conv: block = one canvas row (4 waves x 64 cells)
    hipLaunchKernelGGL(conv_kernel, dim3(NB * NYg), dim3(256), 0, stream,
                       feat_a, feat_r, (const int2*)win, bpack, conv_b, out);
}

// Round 4
// 259.144 us; speedup vs baseline: 1.6601x; 1.1918x over previous
//
#include <hip/hip_runtime.h>
#include <hip/hip_bf16.h>

// Problem constants (from reference)
#define MA 60000
#define PA 20
#define CA 5
#define MR 80000
#define PR 32
#define CR 3
#define NXg 256
#define NYg 256
#define NB 8
#define NCELL (NB * NYg * NXg)   // 524288

typedef __bf16 bf16x8 __attribute__((ext_vector_type(8)));
typedef float  f32x4  __attribute__((ext_vector_type(4)));
typedef float  f4     __attribute__((ext_vector_type(4)));

__device__ __forceinline__ unsigned short f2bf(float f) {
    unsigned int u = __float_as_uint(f);
    u += 0x7fffu + ((u >> 16) & 1u);   // round-to-nearest-even
    return (unsigned short)(u >> 16);
}

// ---------------------------------------------------------------------------
// Winner-map init (-1 everywhere). Interleaved int2 {agent, rg} per cell.
__global__ void __launch_bounds__(256) init_win(int* __restrict__ w, int n) {
    int i = blockIdx.x * 256 + threadIdx.x;
    if (i < n) w[i] = -1;
}

// ---------------------------------------------------------------------------
// Pre-pack conv weights (3,3,128,32) fp32 -> bf16 in MFMA B-fragment order:
// element i = (((tap*4 + kk)*2 + nt)*64 + lane)*8 + j
//   n = nt*16 + (lane&15),  k = kk*32 + (lane>>4)*8 + j
__global__ void __launch_bounds__(256) pack_w(const float* __restrict__ conv_w,
                                              unsigned short* __restrict__ bp) {
    int i = blockIdx.x * 256 + threadIdx.x;
    if (i >= 9 * 4 * 2 * 64 * 8) return;
    int j    = i & 7;
    int lane = (i >> 3) & 63;
    int nt   = (i >> 9) & 1;
    int kk   = (i >> 10) & 3;
    int tap  = i >> 12;
    int n = nt * 16 + (lane & 15);
    int k = kk * 32 + (lane >> 4) * 8 + j;
    bp[i] = f2bf(conv_w[(tap * 128 + k) * 32 + n]);
}

// ---------------------------------------------------------------------------
// Pillar VFE v4: LDS-staged.
// Block = 64 pillars. Phase 1: 256 threads coalesced-load all voxel data
// (64 x 400/384 B) + meta into LDS — lane-parallel MLP, one latency exposure.
// Phase 2: wave wv computes pillars wv, wv+4, ... (lane = output channel),
// reading points from LDS (broadcast ds_read_b128), scalar group-skip on np.
template <int CIN, int CF, int PMAX>
__global__ void __launch_bounds__(256) vfe_kernel(
    const float* __restrict__ vox, const int* __restrict__ coors,
    const int* __restrict__ npts, const float* __restrict__ W,
    const float* __restrict__ bias, unsigned short* __restrict__ feat,
    int* __restrict__ win, int M, int which)
{
    constexpr int G   = 64;                    // pillars per block
    constexpr int NF4 = (PMAX * CIN) / 4;      // f4 per pillar (25 / 24)
    constexpr int NG  = (PMAX + 3) / 4;        // point groups of 4

    __shared__ f4  sq[G * NF4];                // 25.6 / 24.6 KB
    __shared__ int smeta[G * 4];               // np, cb, cy, cx

    int tid  = threadIdx.x;
    int wv   = tid >> 6;
    int lane = tid & 63;
    int base = blockIdx.x * G;
    int cnt  = M - base; cnt = cnt > G ? G : cnt;

    // ---- Phase 1: coalesced staging ----
    {
        const f4* gv = (const f4*)(vox) + (size_t)base * NF4;
        int total = cnt * NF4;
        for (int i = tid; i < total; i += 256) sq[i] = gv[i];
        if (tid < cnt) {
            int np = npts[base + tid];
            np = np < 1 ? 1 : (np > PMAX ? PMAX : np);
            smeta[tid * 4 + 0] = np;
            smeta[tid * 4 + 1] = coors[(base + tid) * 3 + 0];
            smeta[tid * 4 + 2] = coors[(base + tid) * 3 + 1];
            smeta[tid * 4 + 3] = coors[(base + tid) * 3 + 2];
        }
    }

    // per-lane weight column + effective (folded) weights (L2-hot)
    float wc[CF];
#pragma unroll
    for (int c = 0; c < CF; ++c) wc[c] = W[c * 64 + lane];
    float bd = bias[lane];
    float we[CIN];
    we[0] = wc[0] + wc[CIN + 0] + wc[CIN + 3];
    we[1] = wc[1] + wc[CIN + 1] + wc[CIN + 4];
    we[2] = wc[2] + wc[CIN + 2];
#pragma unroll
    for (int c = 3; c < CIN; ++c) we[c] = wc[c];

    __syncthreads();

    // ---- Phase 2: compute 16 pillars per wave ----
    for (int pi = wv; pi < cnt; pi += 4) {
        int np = __builtin_amdgcn_readfirstlane(smeta[pi * 4 + 0]);
        int cb = __builtin_amdgcn_readfirstlane(smeta[pi * 4 + 1]);
        int cy = __builtin_amdgcn_readfirstlane(smeta[pi * 4 + 2]);
        int cx = __builtin_amdgcn_readfirstlane(smeta[pi * 4 + 3]);

        const f4* q = &sq[pi * NF4];

        float sx = 0.f, sy = 0.f, sz = 0.f;
        float sbest = -1e30f;
#pragma unroll
        for (int g = 0; g < NG; ++g) {
            if (np > g * 4) {                 // scalar (wave-uniform) skip
                f4 qq[CIN];                   // 4 points x CIN = CIN f4s
#pragma unroll
                for (int i = 0; i < CIN; ++i) qq[i] = q[g * CIN + i];
#pragma unroll
                for (int j = 0; j < 4; ++j) {
                    const int t0 = j * CIN;
                    float x = qq[(t0 + 0) >> 2][(t0 + 0) & 3];
                    float y = qq[(t0 + 1) >> 2][(t0 + 1) & 3];
                    float z = qq[(t0 + 2) >> 2][(t0 + 2) & 3];
                    bool val = (g * 4 + j) < np;
                    sx += val ? x : 0.0f;
                    sy += val ? y : 0.0f;
                    sz += val ? z : 0.0f;
                    float d = fmaf(x, we[0], fmaf(y, we[1], z * we[2]));
#pragma unroll
                    for (int c = 3; c < CIN; ++c)
                        d = fmaf(qq[(t0 + c) >> 2][(t0 + c) & 3], we[c], d);
                    sbest = val ? fmaxf(sbest, d) : sbest;
                }
            }
        }

        float inv = 1.0f / (float)np;
        float mx = sx * inv, my = sy * inv, mz = sz * inv;
        float xo = (float)cx * 0.3125f + (-39.84375f);   // VX, X_OFF exact
        float yo = (float)cy * 0.3125f + (-19.84375f);
        float off = bd - (mx * wc[CIN + 0] + my * wc[CIN + 1] + mz * wc[CIN + 2])
                       - xo * wc[CIN + 3] - yo * wc[CIN + 4];
        float best = fmaxf(0.0f, sbest + off);

        feat[(size_t)(base + pi) * 64 + lane] = f2bf(best);

        if (lane == 0) {
            // numpy last-write-wins == max pillar index wins; int2 map
            atomicMax(&win[((cb * NYg + cy) * NXg + cx) * 2 + which], base + pi);
        }
    }
}

// ---------------------------------------------------------------------------
// Implicit-GEMM 3x3 conv via MFMA bf16: one wave = 64 cells (4 Mtiles of 16)
// x 32 output channels. Block = one full canvas row (4 waves x 64 cells);
// win row + bpack tap-slice are L1-shared. B fragments loaded once per tap,
// reused by 4 Mtiles; win2 loads hoisted ahead of the dependent gathers.
__global__ void __launch_bounds__(256) conv_kernel(
    const unsigned short* __restrict__ feat_a,
    const unsigned short* __restrict__ feat_r,
    const int2* __restrict__ win2,            // {agent, rg} per cell
    const unsigned short* __restrict__ bpack,
    const float* __restrict__ conv_b,
    float* __restrict__ out)
{
    int lane = threadIdx.x & 63;
    int wv   = threadIdx.x >> 6;
    int row  = blockIdx.x;            // 0..2047  (b*256 + y)
    int y    = row & 255;
    int b    = row >> 8;

    int mrow = lane & 15;             // A-operand row (cell within Mtile)
    int quad = lane >> 4;             // k-chunk of 8
    int xbase = wv * 64;

    bf16x8 z;
#pragma unroll
    for (int i = 0; i < 8; ++i) z[i] = (__bf16)0.0f;

    f32x4 acc0[4], acc1[4];
#pragma unroll
    for (int mt = 0; mt < 4; ++mt) {
        acc0[mt] = (f32x4){0.f, 0.f, 0.f, 0.f};
        acc1[mt] = (f32x4){0.f, 0.f, 0.f, 0.f};
    }

#pragma unroll
    for (int tap = 0; tap < 9; ++tap) {
        const int dy = tap / 3 - 1;
        const int dx = tap % 3 - 1;
        int yy = y + dy;
        if ((unsigned)yy >= (unsigned)NYg) continue;   // wave-uniform skip

        // B fragments for this tap (reused by all 4 Mtiles)
        const unsigned short* bp = bpack + tap * 4096 + lane * 8;
        bf16x8 b00 = *(const bf16x8*)(bp);
        bf16x8 b01 = *(const bf16x8*)(bp + 512);
        bf16x8 b10 = *(const bf16x8*)(bp + 1024);
        bf16x8 b11 = *(const bf16x8*)(bp + 1536);
        bf16x8 b20 = *(const bf16x8*)(bp + 2048);
        bf16x8 b21 = *(const bf16x8*)(bp + 2560);
        bf16x8 b30 = *(const bf16x8*)(bp + 3072);
        bf16x8 b31 = *(const bf16x8*)(bp + 3584);

        int rowoff = ((b << 8) + yy) << 8;             // cell row base

        // hoisted winner loads: 4 independent dwordx2 in flight
        int wa[4], wr[4];
#pragma unroll
        for (int mt = 0; mt < 4; ++mt) {
            int xx = xbase + mt * 16 + mrow + dx;
            bool vx = (unsigned)xx < (unsigned)NXg;    // per-lane edge mask
            wa[mt] = -1; wr[mt] = -1;
            if (vx) {
                int2 w2 = win2[rowoff + xx];
                wa[mt] = w2.x; wr[mt] = w2.y;
            }
        }

#pragma unroll
        for (int mt = 0; mt < 4; ++mt) {
            bf16x8 a0 = z, a1 = z, r0 = z, r1 = z;
            if (wa[mt] >= 0) {
                const unsigned short* pa = feat_a + ((long)wa[mt] << 6) + (quad << 3);
                a0 = *(const bf16x8*)(pa);        // agent k 0..31
                a1 = *(const bf16x8*)(pa + 32);   // agent k 32..63
            }
            if (wr[mt] >= 0) {
                const unsigned short* pr = feat_r + ((long)wr[mt] << 6) + (quad << 3);
                r0 = *(const bf16x8*)(pr);        // rg k 64..95
                r1 = *(const bf16x8*)(pr + 32);   // rg k 96..127
            }

            acc0[mt] = __builtin_amdgcn_mfma_f32_16x16x32_bf16(a0, b00, acc0[mt], 0, 0, 0);
            acc1[mt] = __builtin_amdgcn_mfma_f32_16x16x32_bf16(a0, b01, acc1[mt], 0, 0, 0);
            acc0[mt] = __builtin_amdgcn_mfma_f32_16x16x32_bf16(a1, b10, acc0[mt], 0, 0, 0);
            acc1[mt] = __builtin_amdgcn_mfma_f32_16x16x32_bf16(a1, b11, acc1[mt], 0, 0, 0);
            acc0[mt] = __builtin_amdgcn_mfma_f32_16x16x32_bf16(r0, b20, acc0[mt], 0, 0, 0);
            acc1[mt] = __builtin_amdgcn_mfma_f32_16x16x32_bf16(r0, b21, acc1[mt], 0, 0, 0);
            acc0[mt] = __builtin_amdgcn_mfma_f32_16x16x32_bf16(r1, b30, acc0[mt], 0, 0, 0);
            acc1[mt] = __builtin_amdgcn_mfma_f32_16x16x32_bf16(r1, b31, acc1[mt], 0, 0, 0);
        }
    }

    // D layout: col = lane&15, row = quad*4 + reg (m89/m91-verified)
    int col = lane & 15;
    float bias0 = conv_b[col];
    float bias1 = conv_b[col + 16];
    int cellbase = (((b << 8) + y) << 8) + xbase;
#pragma unroll
    for (int mt = 0; mt < 4; ++mt) {
#pragma unroll
        for (int r = 0; r < 4; ++r) {
            int cell = cellbase + mt * 16 + quad * 4 + r;
            float* o = out + (long)cell * 32;
            o[col]      = acc0[mt][r] + bias0;
            o[col + 16] = acc1[mt][r] + bias1;
        }
    }
}

// ---------------------------------------------------------------------------
extern "C" void kernel_launch(void* const* d_in, const int* in_sizes, int n_in,
                              void* d_out, int out_size, void* d_ws, size_t ws_size,
                              hipStream_t stream)
{
    const float* vox_a  = (const float*)d_in[0];
    const int*   coor_a = (const int*)d_in[1];
    const int*   np_a   = (const int*)d_in[2];
    const float* vox_r  = (const float*)d_in[3];
    const int*   coor_r = (const int*)d_in[4];
    const int*   np_r   = (const int*)d_in[5];
    const float* w_a    = (const float*)d_in[6];
    const float* b_a    = (const float*)d_in[7];
    const float* w_r    = (const float*)d_in[8];
    const float* b_r    = (const float*)d_in[9];
    const float* conv_w = (const float*)d_in[10];
    const float* conv_b = (const float*)d_in[11];
    float* out = (float*)d_out;

    // Workspace layout (16B-aligned offsets), total ~22.2 MB
    char* ws = (char*)d_ws;
    unsigned short* feat_a = (unsigned short*)(ws);                          // 7,680,000 B
    unsigned short* feat_r = (unsigned short*)(ws + 7680000);                // 10,240,000 B
    int* win               = (int*)(ws + 17920000);                          // 4,194,304 B (int2/cell)
    unsigned short* bpack  = (unsigned short*)(ws + 17920000 + 4194304);     // 73,728 B

    // 1) winner map = -1
    hipLaunchKernelGGL(init_win, dim3((2 * NCELL + 255) / 256), dim3(256), 0, stream,
                       win, 2 * NCELL);
    // 2) pack conv weights into B-fragment order (bf16)
    hipLaunchKernelGGL(pack_w, dim3(144), dim3(256), 0, stream, conv_w, bpack);
    // 3) VFE agent: 60000 pillars, 64 pillars/block
    hipLaunchKernelGGL((vfe_kernel<CA, CA + 5, PA>), dim3((MA + 63) / 64), dim3(256), 0, stream,
                       vox_a, coor_a, np_a, w_a, b_a, feat_a, win, MA, 0);
    // 4) VFE rg: 80000 pillars
    hipLaunchKernelGGL((vfe_kernel<CR, CR + 5, PR>), dim3((MR + 63) / 64), dim3(256), 0, stream,
                       vox_r, coor_r, np_r, w_r, b_r, feat_r, win, MR, 1);
    // 5) implicit-GEMM conv: block = one canvas row (4 waves x 64 cells)
    hipLaunchKernelGGL(conv_kernel, dim3(NB * NYg), dim3(256), 0, stream,
                       feat_a, feat_r, (const int2*)win, bpack, conv_b, out);
}

// Round 5
// 242.136 us; speedup vs baseline: 1.7767x; 1.0702x over previous
//
#include <hip/hip_runtime.h>
#include <hip/hip_bf16.h>

// Problem constants (from reference)
#define MA 60000
#define PA 20
#define CA 5
#define MR 80000
#define PR 32
#define CR 3
#define NXg 256
#define NYg 256
#define NB 8
#define NCELL (NB * NYg * NXg)   // 524288

typedef __bf16 bf16x8 __attribute__((ext_vector_type(8)));
typedef float  f32x4  __attribute__((ext_vector_type(4)));
typedef float  f4     __attribute__((ext_vector_type(4)));
typedef float  f2     __attribute__((ext_vector_type(2)));

__device__ __forceinline__ unsigned short f2bf(float f) {
    unsigned int u = __float_as_uint(f);
    u += 0x7fffu + ((u >> 16) & 1u);   // round-to-nearest-even
    return (unsigned short)(u >> 16);
}

// ---------------------------------------------------------------------------
__global__ void __launch_bounds__(256) init_win(int* __restrict__ w, int n) {
    int i = blockIdx.x * 256 + threadIdx.x;
    if (i < n) w[i] = -1;
}

// ---------------------------------------------------------------------------
// Pre-pack conv weights (3,3,128,32) fp32 -> bf16 in MFMA B-fragment order:
// offset = tap*4096 + kk*1024 + nt*512 + lane*8 + j
//   n = nt*16 + (lane&15),  k = kk*32 + (lane>>4)*8 + j
__global__ void __launch_bounds__(256) pack_w(const float* __restrict__ conv_w,
                                              unsigned short* __restrict__ bp) {
    int i = blockIdx.x * 256 + threadIdx.x;
    if (i >= 9 * 4 * 2 * 64 * 8) return;
    int j    = i & 7;
    int lane = (i >> 3) & 63;
    int nt   = (i >> 9) & 1;
    int kk   = (i >> 10) & 3;
    int tap  = i >> 12;
    int n = nt * 16 + (lane & 15);
    int k = kk * 32 + (lane >> 4) * 8 + j;
    bp[i] = f2bf(conv_w[(tap * 128 + k) * 32 + n]);
}

// ---------------------------------------------------------------------------
// Pillar VFE v5: LDS-staged voxels + packed-fp32 compute.
// Full groups of 4 points run unmasked as 2 float2 pairs (v_pk_fma/add/max);
// one masked scalar remainder group. Meta loads are uniform scalar loads,
// software-pipelined one pillar ahead.
template <int CIN, int CF, int PMAX>
__global__ void __launch_bounds__(256) vfe_kernel(
    const float* __restrict__ vox, const int* __restrict__ coors,
    const int* __restrict__ npts, const float* __restrict__ W,
    const float* __restrict__ bias, unsigned short* __restrict__ feat,
    int* __restrict__ win, int M, int which)
{
    constexpr int G   = 64;                    // pillars per block
    constexpr int NF4 = (PMAX * CIN) / 4;      // f4 per pillar (25 / 24)

    __shared__ f4 sq[G * NF4];                 // ~25 KB

    int tid  = threadIdx.x;
    int wv   = tid >> 6;
    int lane = tid & 63;
    int base = blockIdx.x * G;
    int cnt  = M - base; cnt = cnt > G ? G : cnt;

    // ---- Phase 1: coalesced staging of raw voxels ----
    {
        const f4* gv = (const f4*)(vox) + (size_t)base * NF4;
        int total = cnt * NF4;
        for (int i = tid; i < total; i += 256) sq[i] = gv[i];
    }

    // per-lane weight column + effective (folded) weights
    float wc[CF];
#pragma unroll
    for (int c = 0; c < CF; ++c) wc[c] = W[c * 64 + lane];
    float bd = bias[lane];
    float we[CIN];
    we[0] = wc[0] + wc[CIN + 0] + wc[CIN + 3];
    we[1] = wc[1] + wc[CIN + 1] + wc[CIN + 4];
    we[2] = wc[2] + wc[CIN + 2];
#pragma unroll
    for (int c = 3; c < CIN; ++c) we[c] = wc[c];
    f2 we2[CIN];
#pragma unroll
    for (int c = 0; c < CIN; ++c) we2[c] = (f2){we[c], we[c]};

    __syncthreads();

    // prefetch meta for first pillar (wave-uniform scalar loads)
    int np_n = 1, cb_n = 0, cy_n = 0, cx_n = 0;
    if (wv < cnt) {
        np_n = npts[base + wv];
        cb_n = coors[(base + wv) * 3 + 0];
        cy_n = coors[(base + wv) * 3 + 1];
        cx_n = coors[(base + wv) * 3 + 2];
    }

    // ---- Phase 2: 16 pillars per wave ----
    for (int pi = wv; pi < cnt; pi += 4) {
        int np = np_n, cb = cb_n, cy = cy_n, cx = cx_n;
        int pn = pi + 4;
        if (pn < cnt) {                       // prefetch next pillar's meta
            np_n = npts[base + pn];
            cb_n = coors[pn * 3 + base * 3 + 0];
            cy_n = coors[pn * 3 + base * 3 + 1];
            cx_n = coors[pn * 3 + base * 3 + 2];
        }
        np = np < 1 ? 1 : (np > PMAX ? PMAX : np);
        int nfull = np >> 2, rem = np & 3;

        const f4* q = &sq[pi * NF4];

        f2 sx2 = {0.f, 0.f}, sy2 = {0.f, 0.f}, sz2 = {0.f, 0.f};
        f2 b2  = {-1e30f, -1e30f};

        for (int g = 0; g < nfull; ++g) {     // unmasked full groups
            f4 qq[CIN];
#pragma unroll
            for (int i = 0; i < CIN; ++i) qq[i] = q[g * CIN + i];
#pragma unroll
            for (int h = 0; h < 2; ++h) {     // 2 points per pk-instruction
                const int t0 = (2 * h) * CIN, t1 = (2 * h + 1) * CIN;
                f2 x2 = {qq[(t0 + 0) >> 2][(t0 + 0) & 3], qq[(t1 + 0) >> 2][(t1 + 0) & 3]};
                f2 y2 = {qq[(t0 + 1) >> 2][(t0 + 1) & 3], qq[(t1 + 1) >> 2][(t1 + 1) & 3]};
                f2 z2 = {qq[(t0 + 2) >> 2][(t0 + 2) & 3], qq[(t1 + 2) >> 2][(t1 + 2) & 3]};
                sx2 += x2; sy2 += y2; sz2 += z2;
                f2 d2 = x2 * we2[0] + y2 * we2[1] + z2 * we2[2];
#pragma unroll
                for (int c = 3; c < CIN; ++c)
                    d2 += (f2){qq[(t0 + c) >> 2][(t0 + c) & 3],
                               qq[(t1 + c) >> 2][(t1 + c) & 3]} * we2[c];
                b2 = __builtin_elementwise_max(b2, d2);
            }
        }

        float sxr = 0.f, syr = 0.f, szr = 0.f, sbr = -1e30f;
        if (rem) {                            // masked remainder group
            f4 qq[CIN];
#pragma unroll
            for (int i = 0; i < CIN; ++i) qq[i] = q[nfull * CIN + i];
#pragma unroll
            for (int j = 0; j < 3; ++j) {
                const int t0 = j * CIN;
                float x = qq[(t0 + 0) >> 2][(t0 + 0) & 3];
                float y = qq[(t0 + 1) >> 2][(t0 + 1) & 3];
                float z = qq[(t0 + 2) >> 2][(t0 + 2) & 3];
                bool val = j < rem;
                sxr += val ? x : 0.0f;
                syr += val ? y : 0.0f;
                szr += val ? z : 0.0f;
                float d = fmaf(x, we[0], fmaf(y, we[1], z * we[2]));
#pragma unroll
                for (int c = 3; c < CIN; ++c)
                    d = fmaf(qq[(t0 + c) >> 2][(t0 + c) & 3], we[c], d);
                sbr = val ? fmaxf(sbr, d) : sbr;
            }
        }

        float sx = sx2[0] + sx2[1] + sxr;
        float sy = sy2[0] + sy2[1] + syr;
        float sz = sz2[0] + sz2[1] + szr;
        float sbest = fmaxf(fmaxf(b2[0], b2[1]), sbr);

        float inv = 1.0f / (float)np;
        float mx = sx * inv, my = sy * inv, mz = sz * inv;
        float xo = (float)cx * 0.3125f + (-39.84375f);   // VX, X_OFF exact
        float yo = (float)cy * 0.3125f + (-19.84375f);
        float off = bd - (mx * wc[CIN + 0] + my * wc[CIN + 1] + mz * wc[CIN + 2])
                       - xo * wc[CIN + 3] - yo * wc[CIN + 4];
        float best = fmaxf(0.0f, sbest + off);

        feat[(size_t)(base + pi) * 64 + lane] = f2bf(best);

        if (lane == 0) {
            // numpy last-write-wins == max pillar index wins; int2 map
            atomicMax(&win[((cb * NYg + cy) * NXg + cx) * 2 + which], base + pi);
        }
    }
}

// ---------------------------------------------------------------------------
// Conv v3: dense LDS canvas staging. Block = 4 output rows x 64 cells.
// Stage the 6x66-cell halo region through the winner map into LDS (zero-fill
// empties/OOB), channel-split into two phases (agent 64ch, then rg 64ch) so
// LDS = 396 cells * 144 B = 57 KB -> 2 blocks/CU. Compute phases read
// A-fragments via ds_read_b128 (cell stride 144 B = even bank spread) and
// accumulate 288 MFMAs across both phases. No winner indirection in the
// MFMA loop; dy-row reuse is captured in LDS instead of 3x HBM re-fetch.
__global__ void __launch_bounds__(256) conv_kernel(
    const unsigned short* __restrict__ feat_a,
    const unsigned short* __restrict__ feat_r,
    const int2* __restrict__ win2,            // {agent, rg} per cell
    const unsigned short* __restrict__ bpack,
    const float* __restrict__ conv_b,
    float* __restrict__ out)
{
    __shared__ uint4 sA[396 * 9];             // 57,024 B

    int tid  = threadIdx.x;
    int lane = tid & 63;
    int wv   = tid >> 6;
    int bid  = blockIdx.x;
    int xg = bid & 3, yg = (bid >> 2) & 63, b = bid >> 8;
    int x0 = xg * 64, y0 = yg * 4;
    int mrow = lane & 15, quad = lane >> 4;

    f32x4 acc0[4], acc1[4];
#pragma unroll
    for (int mt = 0; mt < 4; ++mt) {
        acc0[mt] = (f32x4){0.f, 0.f, 0.f, 0.f};
        acc1[mt] = (f32x4){0.f, 0.f, 0.f, 0.f};
    }

    int wr_s[2] = {-1, -1};                   // rg winners saved for phase B

    // ---- Phase A staging: agent channels (+ capture rg winner) ----
#pragma unroll
    for (int r = 0; r < 2; ++r) {
        int cell = tid + r * 256;
        if (cell < 396) {
            int iy = cell / 66, ix = cell - iy * 66;
            int yy = y0 - 1 + iy, xx = x0 - 1 + ix;
            int wa = -1;
            if ((unsigned)yy < 256u && (unsigned)xx < 256u) {
                int2 w2 = win2[(((b << 8) + yy) << 8) + xx];
                wa = w2.x; wr_s[r] = w2.y;
            }
            uint4* dst = &sA[cell * 9];
            if (wa >= 0) {
                const uint4* src = (const uint4*)(feat_a + ((long)wa << 6));
#pragma unroll
                for (int s = 0; s < 8; ++s) dst[s] = src[s];
            } else {
                uint4 z = {0, 0, 0, 0};
#pragma unroll
                for (int s = 0; s < 8; ++s) dst[s] = z;
            }
        }
    }
    __syncthreads();

    // ---- Phase A compute: B chunks kk=0,1 (agent k 0..63) ----
#pragma unroll
    for (int tap = 0; tap < 9; ++tap) {
        const int dyo = tap / 3, dxo = tap % 3;
        const unsigned short* bp = bpack + tap * 4096 + lane * 8;
        bf16x8 b00 = *(const bf16x8*)(bp);
        bf16x8 b01 = *(const bf16x8*)(bp + 512);
        bf16x8 b10 = *(const bf16x8*)(bp + 1024);
        bf16x8 b11 = *(const bf16x8*)(bp + 1536);
        int iy = wv + dyo;
#pragma unroll
        for (int mt = 0; mt < 4; ++mt) {
            int ix = mt * 16 + mrow + dxo;
            const uint4* ap = &sA[(iy * 66 + ix) * 9 + quad];
            bf16x8 a0 = *(const bf16x8*)(ap);       // ch quad*8..    (k 0..31)
            bf16x8 a1 = *(const bf16x8*)(ap + 4);   // ch 32+quad*8  (k 32..63)
            acc0[mt] = __builtin_amdgcn_mfma_f32_16x16x32_bf16(a0, b00, acc0[mt], 0, 0, 0);
            acc1[mt] = __builtin_amdgcn_mfma_f32_16x16x32_bf16(a0, b01, acc1[mt], 0, 0, 0);
            acc0[mt] = __builtin_amdgcn_mfma_f32_16x16x32_bf16(a1, b10, acc0[mt], 0, 0, 0);
            acc1[mt] = __builtin_amdgcn_mfma_f32_16x16x32_bf16(a1, b11, acc1[mt], 0, 0, 0);
        }
    }
    __syncthreads();

    // ---- Phase B staging: rg channels (winners already in regs) ----
#pragma unroll
    for (int r = 0; r < 2; ++r) {
        int cell = tid + r * 256;
        if (cell < 396) {
            uint4* dst = &sA[cell * 9];
            if (wr_s[r] >= 0) {
                const uint4* src = (const uint4*)(feat_r + ((long)wr_s[r] << 6));
#pragma unroll
                for (int s = 0; s < 8; ++s) dst[s] = src[s];
            } else {
                uint4 z = {0, 0, 0, 0};
#pragma unroll
                for (int s = 0; s < 8; ++s) dst[s] = z;
            }
        }
    }
    __syncthreads();

    // ---- Phase B compute: B chunks kk=2,3 (rg k 64..127) ----
#pragma unroll
    for (int tap = 0; tap < 9; ++tap) {
        const int dyo = tap / 3, dxo = tap % 3;
        const unsigned short* bp = bpack + tap * 4096 + 2048 + lane * 8;
        bf16x8 b20 = *(const bf16x8*)(bp);
        bf16x8 b21 = *(const bf16x8*)(bp + 512);
        bf16x8 b30 = *(const bf16x8*)(bp + 1024);
        bf16x8 b31 = *(const bf16x8*)(bp + 1536);
        int iy = wv + dyo;
#pragma unroll
        for (int mt = 0; mt < 4; ++mt) {
            int ix = mt * 16 + mrow + dxo;
            const uint4* ap = &sA[(iy * 66 + ix) * 9 + quad];
            bf16x8 r0 = *(const bf16x8*)(ap);       // rg ch quad*8   (k 64..95)
            bf16x8 r1 = *(const bf16x8*)(ap + 4);   // rg ch 32+..    (k 96..127)
            acc0[mt] = __builtin_amdgcn_mfma_f32_16x16x32_bf16(r0, b20, acc0[mt], 0, 0, 0);
            acc1[mt] = __builtin_amdgcn_mfma_f32_16x16x32_bf16(r0, b21, acc1[mt], 0, 0, 0);
            acc0[mt] = __builtin_amdgcn_mfma_f32_16x16x32_bf16(r1, b30, acc0[mt], 0, 0, 0);
            acc1[mt] = __builtin_amdgcn_mfma_f32_16x16x32_bf16(r1, b31, acc1[mt], 0, 0, 0);
        }
    }

    // ---- Epilogue: D layout col=lane&15, row=quad*4+reg ----
    int col = lane & 15;
    float bias0 = conv_b[col];
    float bias1 = conv_b[col + 16];
    int cellbase = ((((b << 8) + y0 + wv)) << 8) + x0;
#pragma unroll
    for (int mt = 0; mt < 4; ++mt) {
#pragma unroll
        for (int r = 0; r < 4; ++r) {
            int cell = cellbase + mt * 16 + quad * 4 + r;
            float* o = out + (long)cell * 32;
            o[col]      = acc0[mt][r] + bias0;
            o[col + 16] = acc1[mt][r] + bias1;
        }
    }
}

// ---------------------------------------------------------------------------
extern "C" void kernel_launch(void* const* d_in, const int* in_sizes, int n_in,
                              void* d_out, int out_size, void* d_ws, size_t ws_size,
                              hipStream_t stream)
{
    const float* vox_a  = (const float*)d_in[0];
    const int*   coor_a = (const int*)d_in[1];
    const int*   np_a   = (const int*)d_in[2];
    const float* vox_r  = (const float*)d_in[3];
    const int*   coor_r = (const int*)d_in[4];
    const int*   np_r   = (const int*)d_in[5];
    const float* w_a    = (const float*)d_in[6];
    const float* b_a    = (const float*)d_in[7];
    const float* w_r    = (const float*)d_in[8];
    const float* b_r    = (const float*)d_in[9];
    const float* conv_w = (const float*)d_in[10];
    const float* conv_b = (const float*)d_in[11];
    float* out = (float*)d_out;

    // Workspace layout (16B-aligned offsets), total ~22.2 MB
    char* ws = (char*)d_ws;
    unsigned short* feat_a = (unsigned short*)(ws);                          // 7,680,000 B
    unsigned short* feat_r = (unsigned short*)(ws + 7680000);                // 10,240,000 B
    int* win               = (int*)(ws + 17920000);                          // 4,194,304 B (int2/cell)
    unsigned short* bpack  = (unsigned short*)(ws + 17920000 + 4194304);     // 73,728 B

    // 1) winner map = -1
    hipLaunchKernelGGL(init_win, dim3((2 * NCELL + 255) / 256), dim3(256), 0, stream,
                       win, 2 * NCELL);
    // 2) pack conv weights into B-fragment order (bf16)
    hipLaunchKernelGGL(pack_w, dim3(144), dim3(256), 0, stream, conv_w, bpack);
    // 3) VFE agent: 60000 pillars, 64 pillars/block
    hipLaunchKernelGGL((vfe_kernel<CA, CA + 5, PA>), dim3((MA + 63) / 64), dim3(256), 0, stream,
                       vox_a, coor_a, np_a, w_a, b_a, feat_a, win, MA, 0);
    // 4) VFE rg: 80000 pillars
    hipLaunchKernelGGL((vfe_kernel<CR, CR + 5, PR>), dim3((MR + 63) / 64), dim3(256), 0, stream,
                       vox_r, coor_r, np_r, w_r, b_r, feat_r, win, MR, 1);
    // 5) conv: block = 4 rows x 64 cells, dense LDS staging
    hipLaunchKernelGGL(conv_kernel, dim3(2048), dim3(256), 0, stream,
                       feat_a, feat_r, (const int2*)win, bpack, conv_b, out);
}

// Round 6
// 233.131 us; speedup vs baseline: 1.8453x; 1.0386x over previous
//
#include <hip/hip_runtime.h>
#include <hip/hip_bf16.h>

// Problem constants (from reference)
#define MA 60000
#define PA 20
#define CA 5
#define MR 80000
#define PR 32
#define CR 3
#define NXg 256
#define NYg 256
#define NB 8
#define NCELL (NB * NYg * NXg)   // 524288

typedef __bf16 bf16x8 __attribute__((ext_vector_type(8)));
typedef float  f32x4  __attribute__((ext_vector_type(4)));
typedef float  f4     __attribute__((ext_vector_type(4)));
typedef float  f2     __attribute__((ext_vector_type(2)));

__device__ __forceinline__ unsigned short f2bf(float f) {
    unsigned int u = __float_as_uint(f);
    u += 0x7fffu + ((u >> 16) & 1u);   // round-to-nearest-even
    return (unsigned short)(u >> 16);
}

// ---------------------------------------------------------------------------
__global__ void __launch_bounds__(256) init_win(int* __restrict__ w, int n) {
    int i = blockIdx.x * 256 + threadIdx.x;
    if (i < n) w[i] = -1;
}

// ---------------------------------------------------------------------------
// Pre-pack conv weights (3,3,128,32) fp32 -> bf16 in MFMA B-fragment order:
// offset = tap*4096 + kk*1024 + nt*512 + lane*8 + j
//   n = nt*16 + (lane&15),  k = kk*32 + (lane>>4)*8 + j
__global__ void __launch_bounds__(256) pack_w(const float* __restrict__ conv_w,
                                              unsigned short* __restrict__ bp) {
    int i = blockIdx.x * 256 + threadIdx.x;
    if (i >= 9 * 4 * 2 * 64 * 8) return;
    int j    = i & 7;
    int lane = (i >> 3) & 63;
    int nt   = (i >> 9) & 1;
    int kk   = (i >> 10) & 3;
    int tap  = i >> 12;
    int n = nt * 16 + (lane & 15);
    int k = kk * 32 + (lane >> 4) * 8 + j;
    bp[i] = f2bf(conv_w[(tap * 128 + k) * 32 + n]);
}

// ---------------------------------------------------------------------------
// Pillar VFE v6: LDS-staged voxels; per-pillar compute in two HALVES. Each
// half hoists ALL its LDS f4 loads into registers with a compile-time trip
// (one batched latency exposure), then computes groups-of-4 points with
// wave-uniform skips and packed-fp32 math (mask = 0/1 fma, max-penalty).
template <int CIN, int CF, int PMAX>
__global__ void __launch_bounds__(256) vfe_kernel(
    const float* __restrict__ vox, const int* __restrict__ coors,
    const int* __restrict__ npts, const float* __restrict__ W,
    const float* __restrict__ bias, unsigned short* __restrict__ feat,
    int* __restrict__ win, int M, int which)
{
    constexpr int G   = 64;                    // pillars per block
    constexpr int NF4 = (PMAX * CIN) / 4;      // f4 per pillar (25 / 24)
    constexpr int NG  = PMAX / 4;              // point groups of 4 (5 / 8)
    constexpr int NG1 = (NG + 1) / 2;          // half-1 groups (3 / 4)
    constexpr int NG2 = NG - NG1;              // half-2 groups (2 / 4)
    constexpr int H1F = NG1 * CIN;             // half-1 f4 count (15 / 12)
    constexpr int H2F = NF4 - H1F;             // half-2 f4 count (10 / 12)

    __shared__ f4 sq[G * NF4];                 // ~25 KB

    int tid  = threadIdx.x;
    int wv   = tid >> 6;
    int lane = tid & 63;
    int base = blockIdx.x * G;
    int cnt  = M - base; cnt = cnt > G ? G : cnt;

    // ---- Phase 1: coalesced staging of raw voxels ----
    {
        const f4* gv = (const f4*)(vox) + (size_t)base * NF4;
        int total = cnt * NF4;
        for (int i = tid; i < total; i += 256) sq[i] = gv[i];
    }

    // per-lane weight column + effective (folded) weights
    float wc[CF];
#pragma unroll
    for (int c = 0; c < CF; ++c) wc[c] = W[c * 64 + lane];
    float bd = bias[lane];
    float we[CIN];
    we[0] = wc[0] + wc[CIN + 0] + wc[CIN + 3];
    we[1] = wc[1] + wc[CIN + 1] + wc[CIN + 4];
    we[2] = wc[2] + wc[CIN + 2];
#pragma unroll
    for (int c = 3; c < CIN; ++c) we[c] = wc[c];
    f2 we2[CIN];
#pragma unroll
    for (int c = 0; c < CIN; ++c) we2[c] = (f2){we[c], we[c]};

    __syncthreads();

    // prefetch meta for first pillar (wave-uniform scalar loads)
    int np_n = 1, cb_n = 0, cy_n = 0, cx_n = 0;
    if (wv < cnt) {
        np_n = npts[base + wv];
        cb_n = coors[(base + wv) * 3 + 0];
        cy_n = coors[(base + wv) * 3 + 1];
        cx_n = coors[(base + wv) * 3 + 2];
    }

    // ---- Phase 2: 16 pillars per wave ----
    for (int pi = wv; pi < cnt; pi += 4) {
        int np = np_n, cb = cb_n, cy = cy_n, cx = cx_n;
        int pn = pi + 4;
        if (pn < cnt) {                       // prefetch next pillar's meta
            np_n = npts[base + pn];
            cb_n = coors[(base + pn) * 3 + 0];
            cy_n = coors[(base + pn) * 3 + 1];
            cx_n = coors[(base + pn) * 3 + 2];
        }
        np = np < 1 ? 1 : (np > PMAX ? PMAX : np);

        const f4* q = &sq[pi * NF4];

        f2 sx2 = {0.f, 0.f}, sy2 = {0.f, 0.f}, sz2 = {0.f, 0.f};
        f2 b2  = {-1e30f, -1e30f};

        // ================= half 1: groups [0, NG1) =================
        {
            f4 qa[H1F];
#pragma unroll
            for (int i = 0; i < H1F; ++i) qa[i] = q[i];   // batched LDS loads
#pragma unroll
            for (int g = 0; g < NG1; ++g) {
                if (np > g * 4) {             // wave-uniform skip
#pragma unroll
                    for (int h = 0; h < 2; ++h) {
                        const int p0 = g * 4 + 2 * h, p1 = p0 + 1;
                        const int t0 = p0 * CIN, t1 = p1 * CIN;
                        f2 x2 = {qa[(t0+0)>>2][(t0+0)&3], qa[(t1+0)>>2][(t1+0)&3]};
                        f2 y2 = {qa[(t0+1)>>2][(t0+1)&3], qa[(t1+1)>>2][(t1+1)&3]};
                        f2 z2 = {qa[(t0+2)>>2][(t0+2)&3], qa[(t1+2)>>2][(t1+2)&3]};
                        f2 mv = {p0 < np ? 1.0f : 0.0f, p1 < np ? 1.0f : 0.0f};
                        f2 pe = {p0 < np ? 0.0f : -2e30f, p1 < np ? 0.0f : -2e30f};
                        sx2 += x2 * mv; sy2 += y2 * mv; sz2 += z2 * mv;
                        f2 d2 = x2 * we2[0] + y2 * we2[1] + z2 * we2[2];
#pragma unroll
                        for (int c = 3; c < CIN; ++c)
                            d2 += (f2){qa[(t0+c)>>2][(t0+c)&3],
                                       qa[(t1+c)>>2][(t1+c)&3]} * we2[c];
                        b2 = __builtin_elementwise_max(b2, d2 + pe);
                    }
                }
            }
        }
        // ================= half 2: groups [NG1, NG) ================
        if (np > NG1 * 4) {                   // wave-uniform skip of whole half
            f4 qb[H2F];
#pragma unroll
            for (int i = 0; i < H2F; ++i) qb[i] = q[H1F + i];
#pragma unroll
            for (int g = 0; g < NG2; ++g) {
                if (np > (NG1 + g) * 4) {     // wave-uniform skip
#pragma unroll
                    for (int h = 0; h < 2; ++h) {
                        const int p0 = (NG1 + g) * 4 + 2 * h, p1 = p0 + 1;
                        const int t0 = p0 * CIN - H1F * 4, t1 = p1 * CIN - H1F * 4;
                        f2 x2 = {qb[(t0+0)>>2][(t0+0)&3], qb[(t1+0)>>2][(t1+0)&3]};
                        f2 y2 = {qb[(t0+1)>>2][(t0+1)&3], qb[(t1+1)>>2][(t1+1)&3]};
                        f2 z2 = {qb[(t0+2)>>2][(t0+2)&3], qb[(t1+2)>>2][(t1+2)&3]};
                        f2 mv = {p0 < np ? 1.0f : 0.0f, p1 < np ? 1.0f : 0.0f};
                        f2 pe = {p0 < np ? 0.0f : -2e30f, p1 < np ? 0.0f : -2e30f};
                        sx2 += x2 * mv; sy2 += y2 * mv; sz2 += z2 * mv;
                        f2 d2 = x2 * we2[0] + y2 * we2[1] + z2 * we2[2];
#pragma unroll
                        for (int c = 3; c < CIN; ++c)
                            d2 += (f2){qb[(t0+c)>>2][(t0+c)&3],
                                       qb[(t1+c)>>2][(t1+c)&3]} * we2[c];
                        b2 = __builtin_elementwise_max(b2, d2 + pe);
                    }
                }
            }
        }

        float sx = sx2[0] + sx2[1];
        float sy = sy2[0] + sy2[1];
        float sz = sz2[0] + sz2[1];
        float sbest = fmaxf(b2[0], b2[1]);

        float inv = 1.0f / (float)np;
        float mx = sx * inv, my = sy * inv, mz = sz * inv;
        float xo = (float)cx * 0.3125f + (-39.84375f);   // VX, X_OFF exact
        float yo = (float)cy * 0.3125f + (-19.84375f);
        float off = bd - (mx * wc[CIN + 0] + my * wc[CIN + 1] + mz * wc[CIN + 2])
                       - xo * wc[CIN + 3] - yo * wc[CIN + 4];
        float best = fmaxf(0.0f, sbest + off);

        feat[(size_t)(base + pi) * 64 + lane] = f2bf(best);

        if (lane == 0) {
            // numpy last-write-wins == max pillar index wins; int2 map
            atomicMax(&win[((cb * NYg + cy) * NXg + cx) * 2 + which], base + pi);
        }
    }
}

// ---------------------------------------------------------------------------
// Conv v4: 4 channel-phases of 32. Block = 4 output rows x 64 cells.
// Per phase: stage 396 halo cells x 32 ch (64 B) through the winner map into
// LDS (cell stride padded to 5 uint4 = 80 B -> odd 16B-stride, full
// bank-group coverage), then 9 taps x 4 Mtiles x 2 Ntiles MFMA with kk=phase.
// LDS = 31.7 KB -> ~5 blocks/CU co-resident, hiding staging latency.
__global__ void __launch_bounds__(256) conv_kernel(
    const unsigned short* __restrict__ feat_a,
    const unsigned short* __restrict__ feat_r,
    const int2* __restrict__ win2,            // {agent, rg} per cell
    const unsigned short* __restrict__ bpack,
    const float* __restrict__ conv_b,
    float* __restrict__ out)
{
    __shared__ uint4 sA[396 * 5];             // 31,680 B (5th uint4 = pad)

    int tid  = threadIdx.x;
    int lane = tid & 63;
    int wv   = tid >> 6;
    int bid  = blockIdx.x;
    int xg = bid & 3, yg = (bid >> 2) & 63, b = bid >> 8;
    int x0 = xg * 64, y0 = yg * 4;
    int mrow = lane & 15, quad = lane >> 4;

    // winner indices for this thread's (up to) 2 halo cells — loaded ONCE
    int wA[2] = {-1, -1}, wR[2] = {-1, -1};
#pragma unroll
    for (int r = 0; r < 2; ++r) {
        int cell = tid + r * 256;
        if (cell < 396) {
            int iy = cell / 66, ix = cell - iy * 66;
            int yy = y0 - 1 + iy, xx = x0 - 1 + ix;
            if ((unsigned)yy < 256u && (unsigned)xx < 256u) {
                int2 w2 = win2[(((b << 8) + yy) << 8) + xx];
                wA[r] = w2.x; wR[r] = w2.y;
            }
        }
    }

    f32x4 acc0[4], acc1[4];
#pragma unroll
    for (int mt = 0; mt < 4; ++mt) {
        acc0[mt] = (f32x4){0.f, 0.f, 0.f, 0.f};
        acc1[mt] = (f32x4){0.f, 0.f, 0.f, 0.f};
    }

#pragma unroll
    for (int ph = 0; ph < 4; ++ph) {
        const unsigned short* feat = (ph < 2) ? feat_a : feat_r;
        const int half = (ph & 1) * 32;       // channel offset within feat row

        // ---- stage this phase's 32 channels for all 396 halo cells ----
#pragma unroll
        for (int r = 0; r < 2; ++r) {
            int cell = tid + r * 256;
            if (cell < 396) {
                int w = (ph < 2) ? wA[r] : wR[r];
                uint4* dst = &sA[cell * 5];
                if (w >= 0) {
                    const uint4* src = (const uint4*)(feat + ((long)w << 6) + half);
                    dst[0] = src[0]; dst[1] = src[1];
                    dst[2] = src[2]; dst[3] = src[3];
                } else {
                    uint4 zz = {0, 0, 0, 0};
                    dst[0] = zz; dst[1] = zz; dst[2] = zz; dst[3] = zz;
                }
            }
        }
        __syncthreads();

        // ---- compute: kk = ph, 9 taps x 4 Mtiles x 2 Ntiles ----
#pragma unroll
        for (int tap = 0; tap < 9; ++tap) {
            const int dyo = tap / 3, dxo = tap % 3;
            const unsigned short* bp = bpack + tap * 4096 + ph * 1024 + lane * 8;
            bf16x8 bn0 = *(const bf16x8*)(bp);
            bf16x8 bn1 = *(const bf16x8*)(bp + 512);
            int iy = wv + dyo;
#pragma unroll
            for (int mt = 0; mt < 4; ++mt) {
                int ix = mt * 16 + mrow + dxo;
                bf16x8 a = *(const bf16x8*)(&sA[(iy * 66 + ix) * 5 + quad]);
                acc0[mt] = __builtin_amdgcn_mfma_f32_16x16x32_bf16(a, bn0, acc0[mt], 0, 0, 0);
                acc1[mt] = __builtin_amdgcn_mfma_f32_16x16x32_bf16(a, bn1, acc1[mt], 0, 0, 0);
            }
        }
        __syncthreads();
    }

    // ---- Epilogue: D layout col=lane&15, row=quad*4+reg ----
    int col = lane & 15;
    float bias0 = conv_b[col];
    float bias1 = conv_b[col + 16];
    int cellbase = ((((b << 8) + y0 + wv)) << 8) + x0;
#pragma unroll
    for (int mt = 0; mt < 4; ++mt) {
#pragma unroll
        for (int r = 0; r < 4; ++r) {
            int cell = cellbase + mt * 16 + quad * 4 + r;
            float* o = out + (long)cell * 32;
            o[col]      = acc0[mt][r] + bias0;
            o[col + 16] = acc1[mt][r] + bias1;
        }
    }
}

// ---------------------------------------------------------------------------
extern "C" void kernel_launch(void* const* d_in, const int* in_sizes, int n_in,
                              void* d_out, int out_size, void* d_ws, size_t ws_size,
                              hipStream_t stream)
{
    const float* vox_a  = (const float*)d_in[0];
    const int*   coor_a = (const int*)d_in[1];
    const int*   np_a   = (const int*)d_in[2];
    const float* vox_r  = (const float*)d_in[3];
    const int*   coor_r = (const int*)d_in[4];
    const int*   np_r   = (const int*)d_in[5];
    const float* w_a    = (const float*)d_in[6];
    const float* b_a    = (const float*)d_in[7];
    const float* w_r    = (const float*)d_in[8];
    const float* b_r    = (const float*)d_in[9];
    const float* conv_w = (const float*)d_in[10];
    const float* conv_b = (const float*)d_in[11];
    float* out = (float*)d_out;

    // Workspace layout (16B-aligned offsets), total ~22.2 MB
    char* ws = (char*)d_ws;
    unsigned short* feat_a = (unsigned short*)(ws);                          // 7,680,000 B
    unsigned short* feat_r = (unsigned short*)(ws + 7680000);                // 10,240,000 B
    int* win               = (int*)(ws + 17920000);                          // 4,194,304 B (int2/cell)
    unsigned short* bpack  = (unsigned short*)(ws + 17920000 + 4194304);     // 73,728 B

    // 1) winner map = -1
    hipLaunchKernelGGL(init_win, dim3((2 * NCELL + 255) / 256), dim3(256), 0, stream,
                       win, 2 * NCELL);
    // 2) pack conv weights into B-fragment order (bf16)
    hipLaunchKernelGGL(pack_w, dim3(144), dim3(256), 0, stream, conv_w, bpack);
    // 3) VFE agent: 60000 pillars, 64 pillars/block
    hipLaunchKernelGGL((vfe_kernel<CA, CA + 5, PA>), dim3((MA + 63) / 64), dim3(256), 0, stream,
                       vox_a, coor_a, np_a, w_a, b_a, feat_a, win, MA, 0);
    // 4) VFE rg: 80000 pillars
    hipLaunchKernelGGL((vfe_kernel<CR, CR + 5, PR>), dim3((MR + 63) / 64), dim3(256), 0, stream,
                       vox_r, coor_r, np_r, w_r, b_r, feat_r, win, MR, 1);
    // 5) conv v4: block = 4 rows x 64 cells, 4 channel-phases
    hipLaunchKernelGGL(conv_kernel, dim3(2048), dim3(256), 0, stream,
                       feat_a, feat_r, (const int2*)win, bpack, conv_b, out);
}

// Round 7
// 209.727 us; speedup vs baseline: 2.0513x; 1.1116x over previous
//
#include <hip/hip_runtime.h>
#include <hip/hip_bf16.h>

// Problem constants (from reference)
#define MA 60000
#define PA 20
#define CA 5
#define MR 80000
#define PR 32
#define CR 3
#define NXg 256
#define NYg 256
#define NB 8
#define NCELL (NB * NYg * NXg)   // 524288

typedef __bf16 bf16x8 __attribute__((ext_vector_type(8)));
typedef float  f32x4  __attribute__((ext_vector_type(4)));
typedef float  f4     __attribute__((ext_vector_type(4)));
typedef float  f2     __attribute__((ext_vector_type(2)));

__device__ __forceinline__ unsigned short f2bf(float f) {
    unsigned int u = __float_as_uint(f);
    u += 0x7fffu + ((u >> 16) & 1u);   // round-to-nearest-even
    return (unsigned short)(u >> 16);
}

// ---------------------------------------------------------------------------
// prep: winner-map init (blocks [0,4096)) + conv-weight B-fragment pack
// (blocks [4096,4240)). Pack order: offset = tap*4096 + kk*1024 + nt*512 +
// lane*8 + j, with n = nt*16+(lane&15), k = kk*32+(lane>>4)*8+j.
__global__ void __launch_bounds__(256) prep_kernel(int* __restrict__ win,
                                                   const float* __restrict__ conv_w,
                                                   unsigned short* __restrict__ bp) {
    int bid = blockIdx.x, tid = threadIdx.x;
    if (bid < 4096) {
        win[bid * 256 + tid] = -1;             // 2*NCELL = 4096*256 exactly
    } else {
        int i = (bid - 4096) * 256 + tid;      // < 144*256 = 36864 exactly
        int j    = i & 7;
        int lane = (i >> 3) & 63;
        int nt   = (i >> 9) & 1;
        int kk   = (i >> 10) & 3;
        int tap  = i >> 12;
        int n = nt * 16 + (lane & 15);
        int k = kk * 32 + (lane >> 4) * 8 + j;
        bp[i] = f2bf(conv_w[(tap * 128 + k) * 32 + n]);
    }
}

// ---------------------------------------------------------------------------
// Pillar VFE v7 body: channel-major LDS staging + dup-fill, maskless compute.
// LDS layout per pillar: [c][pt] with PMAXp (mult of 8) points per channel.
// Invalid slots [np, 8*ceil(np/8)) hold copies of point 0 -> max unchanged,
// sums corrected by (np8-np)*v0. pk pairs come straight from ds_read_b128.
template <int CIN, int CF, int PMAX, int PMAXp>
__device__ __forceinline__ void vfe_body(
    int bid, const float* __restrict__ vox, const int* __restrict__ coors,
    const int* __restrict__ npts, const float* __restrict__ W,
    const float* __restrict__ bias, unsigned short* __restrict__ feat,
    int* __restrict__ win, int M, int which, f4* sq)
{
    constexpr int PC   = PMAX * CIN;       // floats per pillar (source)
    constexpr int NF4v = PC / 4;           // 25 (agent) / 24 (rg)
    constexpr int SR   = PMAXp * CIN;      // floats per pillar (LDS region)
    constexpr int SR4  = SR / 4;
    constexpr int PP4  = PMAXp / 4;

    float* sf = (float*)sq;
    int tid  = threadIdx.x;
    int wv   = tid >> 6;
    int lane = tid & 63;
    int base = bid * 64;
    int cnt  = M - base; cnt = cnt > 64 ? 64 : cnt;

    // ---- staging: coalesced global f4 -> channel-major LDS scatter ----
    {
        const f4* gv = (const f4*)vox + (size_t)base * NF4v;
        int totf4 = cnt * NF4v;
        for (int i = tid; i < totf4; i += 256) {
            f4 v = gv[i];
            int e = i * 4;                 // PC mult of 4 -> f4 never crosses
            int p = e / PC;
            int u = e - p * PC;
#pragma unroll
            for (int t = 0; t < 4; ++t) {
                int uu = u + t;
                int pt = uu / CIN;
                int c  = uu - pt * CIN;
                sf[p * SR + c * PMAXp + pt] = v[t];
            }
        }
    }

    // per-lane weight column + effective (folded) weights (overlaps staging)
    float wc[CF];
#pragma unroll
    for (int c = 0; c < CF; ++c) wc[c] = W[c * 64 + lane];
    float bd = bias[lane];
    f2 we2[CIN];
    we2[0] = (f2){wc[0] + wc[CIN + 0] + wc[CIN + 3], wc[0] + wc[CIN + 0] + wc[CIN + 3]};
    we2[1] = (f2){wc[1] + wc[CIN + 1] + wc[CIN + 4], wc[1] + wc[CIN + 1] + wc[CIN + 4]};
    we2[2] = (f2){wc[2] + wc[CIN + 2], wc[2] + wc[CIN + 2]};
#pragma unroll
    for (int c = 3; c < CIN; ++c) we2[c] = (f2){wc[c], wc[c]};

    __syncthreads();

    // ---- dup-fill: lane per pillar copies point 0 into [np, np8) ----
    if (tid < cnt) {
        int np = npts[base + tid];
        np = np < 1 ? 1 : (np > PMAX ? PMAX : np);
        int np8 = (np + 7) & ~7;           // <= PMAXp
        float v0[CIN];
#pragma unroll
        for (int c = 0; c < CIN; ++c) v0[c] = sf[tid * SR + c * PMAXp];
        for (int p = np; p < np8; ++p)
#pragma unroll
            for (int c = 0; c < CIN; ++c)
                sf[tid * SR + c * PMAXp + p] = v0[c];
    }
    __syncthreads();

    // ---- meta prefetch (wave-uniform scalar loads) ----
    int np_n = 1, cb_n = 0, cy_n = 0, cx_n = 0;
    if (wv < cnt) {
        np_n = npts[base + wv];
        cb_n = coors[(base + wv) * 3 + 0];
        cy_n = coors[(base + wv) * 3 + 1];
        cx_n = coors[(base + wv) * 3 + 2];
    }

    // ---- compute: 16 pillars per wave, maskless pk math ----
    for (int pi = wv; pi < cnt; pi += 4) {
        int np = np_n, cb = cb_n, cy = cy_n, cx = cx_n;
        int pn = pi + 4;
        if (pn < cnt) {
            np_n = npts[base + pn];
            cb_n = coors[(base + pn) * 3 + 0];
            cy_n = coors[(base + pn) * 3 + 1];
            cx_n = coors[(base + pn) * 3 + 2];
        }
        np = np < 1 ? 1 : (np > PMAX ? PMAX : np);
        int nblk = (np + 7) >> 3;
        float kf = (float)(nblk * 8 - np);

        const f4* pf4 = sq + pi * SR4;
        const float* pf = sf + pi * SR;
        float x0 = pf[0], y0 = pf[PMAXp], z0 = pf[2 * PMAXp];

        f2 sx2 = {0.f, 0.f}, sy2 = {0.f, 0.f}, sz2 = {0.f, 0.f};
        f2 b2  = {-1e30f, -1e30f};

        for (int g = 0; g < nblk; ++g) {   // 8 points per block
            f4 lo[CIN], hi[CIN];
#pragma unroll
            for (int c = 0; c < CIN; ++c) {
                lo[c] = pf4[c * PP4 + g * 2];
                hi[c] = pf4[c * PP4 + g * 2 + 1];
            }
#pragma unroll
            for (int h = 0; h < 2; ++h) {  // lo half, hi half (4 points each)
#pragma unroll
                for (int j = 0; j < 2; ++j) {   // pair within half
                    f2 x2 = h ? (f2){hi[0][2*j], hi[0][2*j+1]} : (f2){lo[0][2*j], lo[0][2*j+1]};
                    f2 y2 = h ? (f2){hi[1][2*j], hi[1][2*j+1]} : (f2){lo[1][2*j], lo[1][2*j+1]};
                    f2 z2 = h ? (f2){hi[2][2*j], hi[2][2*j+1]} : (f2){lo[2][2*j], lo[2][2*j+1]};
                    sx2 += x2; sy2 += y2; sz2 += z2;
                    f2 d2 = x2 * we2[0] + y2 * we2[1] + z2 * we2[2];
#pragma unroll
                    for (int c = 3; c < CIN; ++c) {
                        f2 e2 = h ? (f2){hi[c][2*j], hi[c][2*j+1]} : (f2){lo[c][2*j], lo[c][2*j+1]};
                        d2 += e2 * we2[c];
                    }
                    b2 = __builtin_elementwise_max(b2, d2);
                }
            }
        }

        // dup-corrected sums; max unaffected by dups of point 0
        float sx = sx2[0] + sx2[1] - kf * x0;
        float sy = sy2[0] + sy2[1] - kf * y0;
        float sz = sz2[0] + sz2[1] - kf * z0;
        float sbest = fmaxf(b2[0], b2[1]);

        float inv = 1.0f / (float)np;
        float mx = sx * inv, my = sy * inv, mz = sz * inv;
        float xo = (float)cx * 0.3125f + (-39.84375f);   // VX, X_OFF exact
        float yo = (float)cy * 0.3125f + (-19.84375f);
        float off = bd - (mx * wc[CIN + 0] + my * wc[CIN + 1] + mz * wc[CIN + 2])
                       - xo * wc[CIN + 3] - yo * wc[CIN + 4];
        float best = fmaxf(0.0f, sbest + off);

        feat[(size_t)(base + pi) * 64 + lane] = f2bf(best);

        if (lane == 0) {
            // numpy last-write-wins == max pillar index wins; int2 map
            atomicMax(&win[((cb * NYg + cy) * NXg + cx) * 2 + which], base + pi);
        }
    }
}

// Unified VFE launch: blocks [0, 938) = agent, [938, 2188) = rg.
__global__ void __launch_bounds__(256) vfe_all(
    const float* __restrict__ vox_a, const int* __restrict__ coor_a,
    const int* __restrict__ np_a, const float* __restrict__ w_a,
    const float* __restrict__ b_a, unsigned short* __restrict__ feat_a,
    const float* __restrict__ vox_r, const int* __restrict__ coor_r,
    const int* __restrict__ np_r, const float* __restrict__ w_r,
    const float* __restrict__ b_r, unsigned short* __restrict__ feat_r,
    int* __restrict__ win)
{
    __shared__ f4 sq[64 * 30];             // 30720 B (agent: 64*120 floats)
    constexpr int NBA = (MA + 63) / 64;    // 938
    int bid = blockIdx.x;
    if (bid < NBA)
        vfe_body<CA, CA + 5, PA, 24>(bid, vox_a, coor_a, np_a, w_a, b_a,
                                     feat_a, win, MA, 0, sq);
    else
        vfe_body<CR, CR + 5, PR, 32>(bid - NBA, vox_r, coor_r, np_r, w_r, b_r,
                                     feat_r, win, MR, 1, sq);
}

// ---------------------------------------------------------------------------
// Conv v4 (unchanged from r6): 4 channel-phases of 32, block = 4 rows x 64
// cells, 396-cell halo staged via winner map into LDS (80 B cell stride).
__global__ void __launch_bounds__(256) conv_kernel(
    const unsigned short* __restrict__ feat_a,
    const unsigned short* __restrict__ feat_r,
    const int2* __restrict__ win2,            // {agent, rg} per cell
    const unsigned short* __restrict__ bpack,
    const float* __restrict__ conv_b,
    float* __restrict__ out)
{
    __shared__ uint4 sA[396 * 5];             // 31,680 B (5th uint4 = pad)

    int tid  = threadIdx.x;
    int lane = tid & 63;
    int wv   = tid >> 6;
    int bid  = blockIdx.x;
    int xg = bid & 3, yg = (bid >> 2) & 63, b = bid >> 8;
    int x0 = xg * 64, y0 = yg * 4;
    int mrow = lane & 15, quad = lane >> 4;

    // winner indices for this thread's (up to) 2 halo cells — loaded ONCE
    int wA[2] = {-1, -1}, wR[2] = {-1, -1};
#pragma unroll
    for (int r = 0; r < 2; ++r) {
        int cell = tid + r * 256;
        if (cell < 396) {
            int iy = cell / 66, ix = cell - iy * 66;
            int yy = y0 - 1 + iy, xx = x0 - 1 + ix;
            if ((unsigned)yy < 256u && (unsigned)xx < 256u) {
                int2 w2 = win2[(((b << 8) + yy) << 8) + xx];
                wA[r] = w2.x; wR[r] = w2.y;
            }
        }
    }

    f32x4 acc0[4], acc1[4];
#pragma unroll
    for (int mt = 0; mt < 4; ++mt) {
        acc0[mt] = (f32x4){0.f, 0.f, 0.f, 0.f};
        acc1[mt] = (f32x4){0.f, 0.f, 0.f, 0.f};
    }

#pragma unroll
    for (int ph = 0; ph < 4; ++ph) {
        const unsigned short* feat = (ph < 2) ? feat_a : feat_r;
        const int half = (ph & 1) * 32;       // channel offset within feat row

        // ---- stage this phase's 32 channels for all 396 halo cells ----
#pragma unroll
        for (int r = 0; r < 2; ++r) {
            int cell = tid + r * 256;
            if (cell < 396) {
                int w = (ph < 2) ? wA[r] : wR[r];
                uint4* dst = &sA[cell * 5];
                if (w >= 0) {
                    const uint4* src = (const uint4*)(feat + ((long)w << 6) + half);
                    dst[0] = src[0]; dst[1] = src[1];
                    dst[2] = src[2]; dst[3] = src[3];
                } else {
                    uint4 zz = {0, 0, 0, 0};
                    dst[0] = zz; dst[1] = zz; dst[2] = zz; dst[3] = zz;
                }
            }
        }
        __syncthreads();

        // ---- compute: kk = ph, 9 taps x 4 Mtiles x 2 Ntiles ----
#pragma unroll
        for (int tap = 0; tap < 9; ++tap) {
            const int dyo = tap / 3, dxo = tap % 3;
            const unsigned short* bp = bpack + tap * 4096 + ph * 1024 + lane * 8;
            bf16x8 bn0 = *(const bf16x8*)(bp);
            bf16x8 bn1 = *(const bf16x8*)(bp + 512);
            int iy = wv + dyo;
#pragma unroll
            for (int mt = 0; mt < 4; ++mt) {
                int ix = mt * 16 + mrow + dxo;
                bf16x8 a = *(const bf16x8*)(&sA[(iy * 66 + ix) * 5 + quad]);
                acc0[mt] = __builtin_amdgcn_mfma_f32_16x16x32_bf16(a, bn0, acc0[mt], 0, 0, 0);
                acc1[mt] = __builtin_amdgcn_mfma_f32_16x16x32_bf16(a, bn1, acc1[mt], 0, 0, 0);
            }
        }
        __syncthreads();
    }

    // ---- Epilogue: D layout col=lane&15, row=quad*4+reg ----
    int col = lane & 15;
    float bias0 = conv_b[col];
    float bias1 = conv_b[col + 16];
    int cellbase = ((((b << 8) + y0 + wv)) << 8) + x0;
#pragma unroll
    for (int mt = 0; mt < 4; ++mt) {
#pragma unroll
        for (int r = 0; r < 4; ++r) {
            int cell = cellbase + mt * 16 + quad * 4 + r;
            float* o = out + (long)cell * 32;
            o[col]      = acc0[mt][r] + bias0;
            o[col + 16] = acc1[mt][r] + bias1;
        }
    }
}

// ---------------------------------------------------------------------------
extern "C" void kernel_launch(void* const* d_in, const int* in_sizes, int n_in,
                              void* d_out, int out_size, void* d_ws, size_t ws_size,
                              hipStream_t stream)
{
    const float* vox_a  = (const float*)d_in[0];
    const int*   coor_a = (const int*)d_in[1];
    const int*   np_a   = (const int*)d_in[2];
    const float* vox_r  = (const float*)d_in[3];
    const int*   coor_r = (const int*)d_in[4];
    const int*   np_r   = (const int*)d_in[5];
    const float* w_a    = (const float*)d_in[6];
    const float* b_a    = (const float*)d_in[7];
    const float* w_r    = (const float*)d_in[8];
    const float* b_r    = (const float*)d_in[9];
    const float* conv_w = (const float*)d_in[10];
    const float* conv_b = (const float*)d_in[11];
    float* out = (float*)d_out;

    // Workspace layout (16B-aligned offsets), total ~22.2 MB
    char* ws = (char*)d_ws;
    unsigned short* feat_a = (unsigned short*)(ws);                          // 7,680,000 B
    unsigned short* feat_r = (unsigned short*)(ws + 7680000);                // 10,240,000 B
    int* win               = (int*)(ws + 17920000);                          // 4,194,304 B (int2/cell)
    unsigned short* bpack  = (unsigned short*)(ws + 17920000 + 4194304);     // 73,728 B

    // 1) prep: winner map = -1 (4096 blocks) + weight pack (144 blocks)
    hipLaunchKernelGGL(prep_kernel, dim3(4096 + 144), dim3(256), 0, stream,
                       win, conv_w, bpack);
    // 2) unified VFE: agent blocks then rg blocks
    hipLaunchKernelGGL(vfe_all, dim3((MA + 63) / 64 + (MR + 63) / 64), dim3(256), 0, stream,
                       vox_a, coor_a, np_a, w_a, b_a, feat_a,
                       vox_r, coor_r, np_r, w_r, b_r, feat_r, win);
    // 3) conv v4: block = 4 rows x 64 cells, 4 channel-phases
    hipLaunchKernelGGL(conv_kernel, dim3(2048), dim3(256), 0, stream,
                       feat_a, feat_r, (const int2*)win, bpack, conv_b, out);
}